// Round 1
// baseline (2407.838 us; speedup 1.0000x reference)
//
#include <hip/hip_runtime.h>
#include <hip/hip_bf16.h>
#include <cstdint>

// Problem constants
#define BB 8
#define SS 3840
#define RR (BB*SS)      // 30720 rows
#define DD 256
#define HH 8
#define DH 32
#define LL 4
#define PP 4

// ---------------- elementwise add (float4) ----------------
__global__ __launch_bounds__(256) void add_vec(const float* __restrict__ a,
                                               const float* __restrict__ b,
                                               float* __restrict__ out, int n4) {
    int i = blockIdx.x * 256 + threadIdx.x;
    if (i < n4) {
        float4 x = ((const float4*)a)[i];
        float4 y = ((const float4*)b)[i];
        x.x += y.x; x.y += y.y; x.z += y.z; x.w += y.w;
        ((float4*)out)[i] = x;
    }
}

// ---------------- tiled fp32 GEMM: C[M,N] = A[M,K] @ W[K,N] + bias ----------------
// BM=64, BN=64, BK=16, 256 threads, 4x4 per thread.
// epilogue: relu flag; mask (per-row zeroing, for value GEMM)
__global__ __launch_bounds__(256) void gemm_bias(
    const float* __restrict__ A, const float* __restrict__ W,
    const float* __restrict__ bias, float* __restrict__ C,
    int M, int N, int K, int ldc, int ccol, int relu,
    const unsigned char* __restrict__ mask)
{
    __shared__ float As[16][64];
    __shared__ float Ws[16][64];
    const int bm = blockIdx.x * 64;
    const int bn = blockIdx.y * 64;
    const int tid = threadIdx.x;
    const int tx = tid & 15, ty = tid >> 4;

    const int ar = tid >> 2;          // 0..63 row within tile
    const int ak = (tid & 3) << 2;    // 0,4,8,12
    const int wk = tid >> 4;          // 0..15
    const int wc = (tid & 15) << 2;   // 0..60

    float acc[4][4];
    #pragma unroll
    for (int i = 0; i < 4; ++i)
        #pragma unroll
        for (int j = 0; j < 4; ++j) acc[i][j] = 0.f;

    for (int k0 = 0; k0 < K; k0 += 16) {
        float4 av = *(const float4*)&A[(size_t)(bm + ar) * K + k0 + ak];
        As[ak + 0][ar] = av.x;
        As[ak + 1][ar] = av.y;
        As[ak + 2][ar] = av.z;
        As[ak + 3][ar] = av.w;
        float4 wv = *(const float4*)&W[(size_t)(k0 + wk) * N + bn + wc];
        *(float4*)&Ws[wk][wc] = wv;
        __syncthreads();
        #pragma unroll
        for (int kk = 0; kk < 16; ++kk) {
            const float4 a = *(const float4*)&As[kk][ty << 2];
            const float4 w = *(const float4*)&Ws[kk][tx << 2];
            float a4[4] = {a.x, a.y, a.z, a.w};
            float w4[4] = {w.x, w.y, w.z, w.w};
            #pragma unroll
            for (int i = 0; i < 4; ++i)
                #pragma unroll
                for (int j = 0; j < 4; ++j)
                    acc[i][j] = fmaf(a4[i], w4[j], acc[i][j]);
        }
        __syncthreads();
    }

    #pragma unroll
    for (int i = 0; i < 4; ++i) {
        int row = bm + (ty << 2) + i;
        float mz = 1.f;
        if (mask && mask[row]) mz = 0.f;
        #pragma unroll
        for (int j = 0; j < 4; ++j) {
            int col = bn + (tx << 2) + j;
            float c = acc[i][j] + bias[col];
            if (relu) c = fmaxf(c, 0.f);
            c *= mz;
            C[(size_t)row * ldc + ccol + col] = c;
        }
    }
}

// ---------------- softmax(aw over 16 per head) + loc = ref + off/ts ----------------
// grid: RR blocks, 128 threads; t = h*16 + l*4 + p
__global__ __launch_bounds__(128) void softmax_loc(
    const float* __restrict__ offaw,   // (RR,256): off in cols 0..127, aw-pre in 128..255
    const float* __restrict__ ref,     // (RR, L)
    const int* __restrict__ ts,
    float* __restrict__ loc_out, int loc_stride,
    float* __restrict__ aw_out, int aw_stride)
{
    const int row = blockIdx.x;
    const int t = threadIdx.x;
    const int l = (t >> 2) & 3;
    const float off = offaw[(size_t)row * 256 + t];
    float a = offaw[(size_t)row * 256 + 128 + t];

    float m = a;
    #pragma unroll
    for (int o = 1; o < 16; o <<= 1) m = fmaxf(m, __shfl_xor(m, o));
    float e = __expf(a - m);
    float s = e;
    #pragma unroll
    for (int o = 1; o < 16; o <<= 1) s += __shfl_xor(s, o);

    aw_out[(size_t)row * aw_stride + t] = e / s;
    const float T = (float)ts[l];
    loc_out[(size_t)row * loc_stride + t] = ref[(size_t)row * 4 + l] + off / T;
}

// ---------------- deformable sampling ----------------
// grid: RR blocks, 256 threads (h = t>>5, d = t&31)
__global__ __launch_bounds__(256) void msda_sample(
    const float* __restrict__ value,   // (RR,256) for this call's src
    const float* __restrict__ loc, int loc_stride,
    const float* __restrict__ aw, int aw_stride,
    const int* __restrict__ ts, const int* __restrict__ lsi,
    float* __restrict__ out)
{
    const int row = blockIdx.x;
    const int b = row / SS;
    const int t = threadIdx.x;
    const int h = t >> 5, d = t & 31;

    float acc = 0.f;
    #pragma unroll
    for (int l = 0; l < 4; ++l) {
        const int T = ts[l];
        const int s0 = lsi[l];
        const float* vbase = value + ((size_t)b * SS + s0) * 256 + h * 32 + d;
        const float Tf = (float)T;
        #pragma unroll
        for (int p = 0; p < 4; ++p) {
            const int idx = h * 16 + l * 4 + p;
            const float lc = loc[(size_t)row * loc_stride + idx];
            const float w  = aw[(size_t)row * aw_stride + idx];
            const float pos = lc * Tf - 0.5f;
            const float x0 = floorf(pos);
            const float w1 = pos - x0;
            const int i0 = (int)x0;
            const int i1 = i0 + 1;
            float v0 = (i0 >= 0 && i0 < T) ? vbase[i0 * 256] : 0.f;
            float v1 = (i1 >= 0 && i1 < T) ? vbase[i1 * 256] : 0.f;
            acc = fmaf(w, fmaf(w1, v1 - v0, v0), acc);
        }
    }
    out[(size_t)row * 256 + t] = acc;
}

// ---------------- residual add + layernorm ----------------
// grid: RR blocks, 256 threads (one per column)
__global__ __launch_bounds__(256) void add_ln(
    const float* __restrict__ a, const float* __restrict__ b,
    const float* __restrict__ g, const float* __restrict__ beta,
    float* __restrict__ out)
{
    __shared__ float red[8];
    const int row = blockIdx.x;
    const int t = threadIdx.x;
    const float x = a[(size_t)row * 256 + t] + b[(size_t)row * 256 + t];
    float s1 = x, s2 = x * x;
    #pragma unroll
    for (int o = 32; o > 0; o >>= 1) {
        s1 += __shfl_xor(s1, o);
        s2 += __shfl_xor(s2, o);
    }
    const int wid = t >> 6;
    if ((t & 63) == 0) { red[wid] = s1; red[4 + wid] = s2; }
    __syncthreads();
    const float S1 = red[0] + red[1] + red[2] + red[3];
    const float S2 = red[4] + red[5] + red[6] + red[7];
    const float m = S1 * (1.f / 256.f);
    float v = S2 * (1.f / 256.f) - m * m;
    v = fmaxf(v, 0.f);
    const float r = rsqrtf(v + 1e-5f);
    out[(size_t)row * 256 + t] = (x - m) * r * g[t] + beta[t];
}

extern "C" void kernel_launch(void* const* d_in, const int* in_sizes, int n_in,
                              void* d_out, int out_size, void* d_ws, size_t ws_size,
                              hipStream_t stream) {
    const float* video_src = (const float*)d_in[0];
    const float* audio_src = (const float*)d_in[1];
    const float* video_pos = (const float*)d_in[2];
    const float* audio_pos = (const float*)d_in[3];
    const float* video_ref = (const float*)d_in[4];
    const float* audio_ref = (const float*)d_in[5];
    const int*   video_ts  = (const int*)d_in[6];
    const int*   video_lsi = (const int*)d_in[7];
    const unsigned char* video_mask = (const unsigned char*)d_in[8];
    const int*   audio_ts  = (const int*)d_in[9];
    const int*   audio_lsi = (const int*)d_in[10];
    const unsigned char* audio_mask = (const unsigned char*)d_in[11];
    const float* Wv = (const float*)d_in[12];
    const float* bv = (const float*)d_in[13];
    const float* Wo = (const float*)d_in[14];
    const float* bo = (const float*)d_in[15];
    const float* Wa = (const float*)d_in[16];
    const float* ba = (const float*)d_in[17];
    const float* Wp = (const float*)d_in[18];
    const float* bp = (const float*)d_in[19];
    const float* ln1_g = (const float*)d_in[20];
    const float* ln1_b = (const float*)d_in[21];
    const float* W1 = (const float*)d_in[22];
    const float* b1 = (const float*)d_in[23];
    const float* W2 = (const float*)d_in[24];
    const float* b2 = (const float*)d_in[25];
    const float* ln2_g = (const float*)d_in[26];
    const float* ln2_b = (const float*)d_in[27];

    float* out = (float*)d_out;
    // d_out layout (floats): aav, vaa, v_loc, v_aw, a_loc, a_aw
    const size_t n = (size_t)RR * 256;            // 7,864,320
    float* out_aav  = out;
    float* out_vaa  = out + n;
    float* out_vloc = out + 2 * n;
    float* out_vaw  = out + 2 * n + n / 2;
    float* out_aloc = out + 3 * n;
    float* out_aaw  = out + 3 * n + n / 2;

    // workspace layout (floats), ~300MB total
    float* ws = (float*)d_ws;
    float* video = ws;               // persists
    float* audio = ws + n;           // persists
    float* S0 = ws + 2 * n;          // q / samp
    float* S1 = ws + 3 * n;          // value / ffn h2
    float* S2 = ws + 4 * n;          // offaw / proj (= ffn x)
    float* S3 = ws + 5 * n;          // loc (RR*128), phases 1-2
    float* S5 = ws + 5 * n + n / 2;  // ffn hidden (RR*1024)

    auto gemm = [&](const float* A, const float* W, const float* bias, float* C,
                    int N, int K, int ldc, int ccol, int relu, const unsigned char* mask) {
        dim3 g(RR / 64, N / 64);
        gemm_bias<<<g, 256, 0, stream>>>(A, W, bias, C, RR, N, K, ldc, ccol, relu, mask);
    };

    auto msda = [&](const float* query, const float* src, const float* ref,
                    const int* ts, const int* lsi, const unsigned char* mask,
                    float* loc_out, int loc_stride, float* aw_out, int aw_stride,
                    float* proj_out) {
        gemm(src, Wv, bv, S1, 256, 256, 256, 0, 0, mask);          // value
        gemm(query, Wo, bo, S2, 128, 256, 256, 0, 0, nullptr);     // off  -> S2[:,0:128]
        gemm(query, Wa, ba, S2, 128, 256, 256, 128, 0, nullptr);   // aw   -> S2[:,128:256]
        softmax_loc<<<RR, 128, 0, stream>>>(S2, ref, ts, loc_out, loc_stride, aw_out, aw_stride);
        msda_sample<<<RR, 256, 0, stream>>>(S1, loc_out, loc_stride, aw_out, aw_stride, ts, lsi, S0);
        gemm(S0, Wp, bp, proj_out, 256, 256, 256, 0, 0, nullptr);  // proj
    };

    const int n4 = (int)(n / 4);

    // Phase 1: video self-attention
    add_vec<<<(n4 + 255) / 256, 256, 0, stream>>>(video_src, video_pos, S0, n4);
    msda(S0, video_src, video_ref, video_ts, video_lsi, video_mask,
         S3, 128, S2 + 128, 256, S2);
    add_ln<<<RR, 256, 0, stream>>>(video_src, S2, ln1_g, ln1_b, video);

    // Phase 2: audio self-attention
    add_vec<<<(n4 + 255) / 256, 256, 0, stream>>>(audio_src, audio_pos, S0, n4);
    msda(S0, audio_src, audio_ref, audio_ts, audio_lsi, audio_mask,
         S3, 128, S2 + 128, 256, S2);
    add_ln<<<RR, 256, 0, stream>>>(audio_src, S2, ln1_g, ln1_b, audio);

    // Phase 3: vaa = msda(audio, audio_ref, video, video_ts/lsi/mask) -> a_loc, a_aw
    msda(audio, video, audio_ref, video_ts, video_lsi, video_mask,
         out_aloc, 128, out_aaw, 128, S2);
    // FFN on S2 -> out_vaa
    gemm(S2, W1, b1, S5, 1024, 256, 1024, 0, 1, nullptr);
    gemm(S5, W2, b2, S1, 256, 1024, 256, 0, 0, nullptr);
    add_ln<<<RR, 256, 0, stream>>>(S2, S1, ln2_g, ln2_b, out_vaa);

    // Phase 4: aav = msda(video, video_ref, audio, audio_ts/lsi/mask) -> v_loc, v_aw
    msda(video, audio, video_ref, audio_ts, audio_lsi, audio_mask,
         out_vloc, 128, out_vaw, 128, S2);
    gemm(S2, W1, b1, S5, 1024, 256, 1024, 0, 1, nullptr);
    gemm(S5, W2, b2, S1, 256, 1024, 256, 0, 0, nullptr);
    add_ln<<<RR, 256, 0, stream>>>(S2, S1, ln2_g, ln2_b, out_aav);
}

// Round 2
// 1415.294 us; speedup vs baseline: 1.7013x; 1.7013x over previous
//
#include <hip/hip_runtime.h>
#include <hip/hip_bf16.h>
#include <cstdint>

#define BB 8
#define SS 3840
#define RR (BB*SS)      // 30720 rows

typedef short s16x8 __attribute__((ext_vector_type(8)));
typedef float f32x4 __attribute__((ext_vector_type(4)));

__device__ __forceinline__ ushort f2bf(float f) {
    uint32_t u = __builtin_bit_cast(uint32_t, f);
    u += 0x7FFFu + ((u >> 16) & 1u);
    return (ushort)(u >> 16);
}
__device__ __forceinline__ float bf2f(ushort h) {
    return __builtin_bit_cast(float, (uint32_t)h << 16);
}

#define GLDS16(gp, lp) __builtin_amdgcn_global_load_lds( \
    (const __attribute__((address_space(1))) uint32_t*)(gp), \
    (__attribute__((address_space(3))) uint32_t*)(lp), 16, 0, 0)

// ---------------- weight transpose fp32 -> bf16 : Wt[n][k] = W[k][n] ----------------
__global__ __launch_bounds__(256) void wtrans(const float* __restrict__ W, ushort* __restrict__ Wt,
                                              int K, int N, int noff) {
    int idx = blockIdx.x * 256 + threadIdx.x;
    if (idx >= K * N) return;
    int k = idx / N, n = idx % N;
    Wt[(size_t)(n + noff) * K + k] = f2bf(W[idx]);
}

__global__ void cbias(const float* __restrict__ bo, const float* __restrict__ ba, float* __restrict__ boa) {
    int t = threadIdx.x;
    boa[t] = (t < 128) ? bo[t] : ba[t - 128];
}

// ---------------- pack: src_bf = bf16(src), q_bf = bf16(src+pos) ----------------
__global__ __launch_bounds__(256) void pack2(const float* __restrict__ s, const float* __restrict__ p,
                                             ushort* __restrict__ sb, ushort* __restrict__ qb, int n4) {
    int i = blockIdx.x * 256 + threadIdx.x;
    if (i >= n4) return;
    float4 a = ((const float4*)s)[i];
    float4 b = ((const float4*)p)[i];
    ushort4 u, v;
    u.x = f2bf(a.x); u.y = f2bf(a.y); u.z = f2bf(a.z); u.w = f2bf(a.w);
    v.x = f2bf(a.x + b.x); v.y = f2bf(a.y + b.y); v.z = f2bf(a.z + b.z); v.w = f2bf(a.w + b.w);
    ((ushort4*)sb)[i] = u;
    ((ushort4*)qb)[i] = v;
}

// ---------------- bf16 MFMA GEMM: C[M,N] = A[M,K](bf16) @ Wt[N,K](bf16)^T + bias ----------------
// 128x128 tile, BK=64, 4 waves (2x2), 4x4 frags of 16x16x32 per wave.
// LDS XOR-swizzle (slot ^= row&7) via pre-swizzled global source + swizzled ds_read.
template<int RELU, int WF, int WB, int MASKED>
__global__ __launch_bounds__(256) void gemm_mfma(
    const ushort* __restrict__ A, const ushort* __restrict__ Wt,
    const float* __restrict__ bias,
    float* __restrict__ C, ushort* __restrict__ Cb,
    int N, int K, const unsigned char* __restrict__ mask)
{
    __shared__ ushort As[128 * 64];
    __shared__ ushort Bs[128 * 64];
    const int tid = threadIdx.x;
    const int lane = tid & 63;
    const int wid = tid >> 6;
    const int wr = wid >> 1, wc = wid & 1;
    const int bm = blockIdx.x << 7;
    const int bn = blockIdx.y << 7;
    const int l15 = lane & 15;
    const int l4 = lane >> 4;

    f32x4 acc[4][4] = {};

    for (int k0 = 0; k0 < K; k0 += 64) {
        #pragma unroll
        for (int r = 0; r < 4; ++r) {
            int base = r * 256 + (wid << 6);      // wave-uniform
            int idx = base + lane;
            int row = idx >> 3, sl = idx & 7;
            int ch = sl ^ (row & 7);              // inverse-swizzled global chunk
            GLDS16(&A[(size_t)(bm + row) * K + k0 + ch * 8], &As[base << 3]);
        }
        #pragma unroll
        for (int r = 0; r < 4; ++r) {
            int base = r * 256 + (wid << 6);
            int idx = base + lane;
            int col = idx >> 3, sl = idx & 7;
            int ch = sl ^ (col & 7);
            GLDS16(&Wt[(size_t)(bn + col) * K + k0 + ch * 8], &Bs[base << 3]);
        }
        __syncthreads();
        #pragma unroll
        for (int ks = 0; ks < 2; ++ks) {
            s16x8 af[4], bf[4];
            const int k16 = ks * 4 + l4;
            #pragma unroll
            for (int m = 0; m < 4; ++m) {
                int row = (wr << 6) + (m << 4) + l15;
                af[m] = *(const s16x8*)&As[(row << 6) + ((k16 ^ (row & 7)) << 3)];
            }
            #pragma unroll
            for (int n = 0; n < 4; ++n) {
                int col = (wc << 6) + (n << 4) + l15;
                bf[n] = *(const s16x8*)&Bs[(col << 6) + ((k16 ^ (col & 7)) << 3)];
            }
            #pragma unroll
            for (int m = 0; m < 4; ++m)
                #pragma unroll
                for (int n = 0; n < 4; ++n)
                    acc[m][n] = __builtin_amdgcn_mfma_f32_16x16x32_bf16(af[m], bf[n], acc[m][n], 0, 0, 0);
        }
        __syncthreads();
    }

    #pragma unroll
    for (int m = 0; m < 4; ++m) {
        #pragma unroll
        for (int r = 0; r < 4; ++r) {
            const int row = bm + (wr << 6) + (m << 4) + (l4 << 2) + r;
            const bool mz = MASKED ? (mask[row] != 0) : false;
            #pragma unroll
            for (int n = 0; n < 4; ++n) {
                const int col = bn + (wc << 6) + (n << 4) + l15;
                float c = acc[m][n][r] + bias[col];
                if (RELU) c = fmaxf(c, 0.f);
                if (MASKED && mz) c = 0.f;
                if (WF) C[(size_t)row * N + col] = c;
                if (WB) Cb[(size_t)row * N + col] = f2bf(c);
            }
        }
    }
}

// ---------------- softmax(aw over 16 per head) + loc = ref + off/ts ----------------
__global__ __launch_bounds__(128) void softmax_loc(
    const float* __restrict__ offaw,   // (RR,256): off cols 0..127, aw-pre 128..255
    const float* __restrict__ ref,     // (RR, 4)
    const int* __restrict__ ts,
    float* __restrict__ loc_out, int loc_stride,
    float* __restrict__ aw_out, int aw_stride)
{
    const int row = blockIdx.x;
    const int t = threadIdx.x;
    const int l = (t >> 2) & 3;
    const float off = offaw[(size_t)row * 256 + t];
    float a = offaw[(size_t)row * 256 + 128 + t];

    float m = a;
    #pragma unroll
    for (int o = 1; o < 16; o <<= 1) m = fmaxf(m, __shfl_xor(m, o));
    float e = __expf(a - m);
    float s = e;
    #pragma unroll
    for (int o = 1; o < 16; o <<= 1) s += __shfl_xor(s, o);

    aw_out[(size_t)row * aw_stride + t] = e / s;
    const float T = (float)ts[l];
    loc_out[(size_t)row * loc_stride + t] = ref[(size_t)row * 4 + l] + off / T;
}

// ---------------- deformable sampling (value bf16 -> samp bf16) ----------------
__global__ __launch_bounds__(256) void msda_sample(
    const ushort* __restrict__ value,
    const float* __restrict__ loc, int loc_stride,
    const float* __restrict__ aw, int aw_stride,
    const int* __restrict__ ts, const int* __restrict__ lsi,
    ushort* __restrict__ out)
{
    const int row = blockIdx.x;
    const int b = row / SS;
    const int t = threadIdx.x;
    const int h = t >> 5, d = t & 31;

    float acc = 0.f;
    #pragma unroll
    for (int l = 0; l < 4; ++l) {
        const int T = ts[l];
        const int s0 = lsi[l];
        const ushort* vbase = value + ((size_t)b * SS + s0) * 256 + h * 32 + d;
        const float Tf = (float)T;
        #pragma unroll
        for (int p = 0; p < 4; ++p) {
            const int idx = h * 16 + l * 4 + p;
            const float lc = loc[(size_t)row * loc_stride + idx];
            const float w  = aw[(size_t)row * aw_stride + idx];
            const float pos = lc * Tf - 0.5f;
            const float x0 = floorf(pos);
            const float w1 = pos - x0;
            const int i0 = (int)x0;
            const int i1 = i0 + 1;
            float v0 = (i0 >= 0 && i0 < T) ? bf2f(vbase[(size_t)i0 * 256]) : 0.f;
            float v1 = (i1 >= 0 && i1 < T) ? bf2f(vbase[(size_t)i1 * 256]) : 0.f;
            acc = fmaf(w, fmaf(w1, v1 - v0, v0), acc);
        }
    }
    out[(size_t)row * 256 + t] = f2bf(acc);
}

// ---------------- residual add + layernorm (dual-dtype output) ----------------
template<int WF, int WB>
__global__ __launch_bounds__(256) void add_ln(
    const float* __restrict__ a, const float* __restrict__ b,
    const float* __restrict__ g, const float* __restrict__ beta,
    float* __restrict__ of, ushort* __restrict__ ob)
{
    __shared__ float red[8];
    const int row = blockIdx.x;
    const int t = threadIdx.x;
    const float x = a[(size_t)row * 256 + t] + b[(size_t)row * 256 + t];
    float s1 = x, s2 = x * x;
    #pragma unroll
    for (int o = 32; o > 0; o >>= 1) {
        s1 += __shfl_xor(s1, o);
        s2 += __shfl_xor(s2, o);
    }
    const int wid = t >> 6;
    if ((t & 63) == 0) { red[wid] = s1; red[4 + wid] = s2; }
    __syncthreads();
    const float S1 = red[0] + red[1] + red[2] + red[3];
    const float S2 = red[4] + red[5] + red[6] + red[7];
    const float m = S1 * (1.f / 256.f);
    float v = S2 * (1.f / 256.f) - m * m;
    v = fmaxf(v, 0.f);
    const float r = rsqrtf(v + 1e-5f);
    const float y = (x - m) * r * g[t] + beta[t];
    if (WF) of[(size_t)row * 256 + t] = y;
    if (WB) ob[(size_t)row * 256 + t] = f2bf(y);
}

extern "C" void kernel_launch(void* const* d_in, const int* in_sizes, int n_in,
                              void* d_out, int out_size, void* d_ws, size_t ws_size,
                              hipStream_t stream) {
    const float* video_src = (const float*)d_in[0];
    const float* audio_src = (const float*)d_in[1];
    const float* video_pos = (const float*)d_in[2];
    const float* audio_pos = (const float*)d_in[3];
    const float* video_ref = (const float*)d_in[4];
    const float* audio_ref = (const float*)d_in[5];
    const int*   video_ts  = (const int*)d_in[6];
    const int*   video_lsi = (const int*)d_in[7];
    const unsigned char* video_mask = (const unsigned char*)d_in[8];
    const int*   audio_ts  = (const int*)d_in[9];
    const int*   audio_lsi = (const int*)d_in[10];
    const unsigned char* audio_mask = (const unsigned char*)d_in[11];
    const float* Wv = (const float*)d_in[12];
    const float* bv = (const float*)d_in[13];
    const float* Wo = (const float*)d_in[14];
    const float* bo = (const float*)d_in[15];
    const float* Wa = (const float*)d_in[16];
    const float* ba = (const float*)d_in[17];
    const float* Wp = (const float*)d_in[18];
    const float* bp = (const float*)d_in[19];
    const float* ln1_g = (const float*)d_in[20];
    const float* ln1_b = (const float*)d_in[21];
    const float* W1 = (const float*)d_in[22];
    const float* b1 = (const float*)d_in[23];
    const float* W2 = (const float*)d_in[24];
    const float* b2 = (const float*)d_in[25];
    const float* ln2_g = (const float*)d_in[26];
    const float* ln2_b = (const float*)d_in[27];

    float* out = (float*)d_out;
    const size_t n = (size_t)RR * 256;            // 7,864,320 elems
    float* out_aav  = out;
    float* out_vaa  = out + n;
    float* out_vloc = out + 2 * n;
    float* out_vaw  = out + 2 * n + n / 2;
    float* out_aloc = out + 3 * n;
    float* out_aaw  = out + 3 * n + n / 2;

    // workspace (byte offsets; total 24n + ~1.5MB ~= 190MB)
    char* base = (char*)d_ws;
    ushort* video_b = (ushort*)(base + 0 * n);
    ushort* audio_b = (ushort*)(base + 2 * n);
    ushort* src_b   = (ushort*)(base + 4 * n);
    ushort* q_b     = (ushort*)(base + 6 * n);
    float*  loc_tmp = (float*) (base + 8 * n);    // RR*128 f32
    ushort* value_b = (ushort*)(base + 10 * n);
    float*  offaw   = (float*) (base + 12 * n);   // RR*256 f32
    ushort* samp_b  = (ushort*)(base + 16 * n);
    float*  proj_f  = (float*) (base + 18 * n);
    ushort* proj_b  = (ushort*)(base + 22 * n);
    ushort* hid_b   = (ushort*)(base + 4 * n);    // RR*1024 bf16, aliases [4n,12n)
    float*  ffnout  = (float*) (base + 12 * n);   // aliases offaw
    ushort* Wvt  = (ushort*)(base + 24 * n);
    ushort* Woat = Wvt + 65536;
    ushort* Wpt  = Woat + 65536;
    ushort* W1t  = Wpt + 65536;      // 256*1024
    ushort* W2t  = W1t + 262144;     // 1024*256
    float*  boa  = (float*)(W2t + 262144);

    // ---- weights: transpose + convert (once per launch, tiny) ----
    wtrans<<<256, 256, 0, stream>>>(Wv, Wvt, 256, 256, 0);
    wtrans<<<128, 256, 0, stream>>>(Wo, Woat, 256, 128, 0);
    wtrans<<<128, 256, 0, stream>>>(Wa, Woat, 256, 128, 128);
    wtrans<<<256, 256, 0, stream>>>(Wp, Wpt, 256, 256, 0);
    wtrans<<<1024, 256, 0, stream>>>(W1, W1t, 256, 1024, 0);
    wtrans<<<1024, 256, 0, stream>>>(W2, W2t, 1024, 256, 0);
    cbias<<<1, 256, 0, stream>>>(bo, ba, boa);

    const int n4 = (int)(n / 4);
    const dim3 g2(240, 2), g8(240, 8);

    auto msda = [&](const ushort* qb, const ushort* srcb, const float* ref,
                    const int* ts, const int* lsi, const unsigned char* mk,
                    float* loco, int ls, float* awo, int as_,
                    float* pf, ushort* pb) {
        gemm_mfma<0,0,1,1><<<g2, 256, 0, stream>>>(srcb, Wvt, bv, nullptr, value_b, 256, 256, mk);
        gemm_mfma<0,1,0,0><<<g2, 256, 0, stream>>>(qb, Woat, boa, offaw, nullptr, 256, 256, nullptr);
        softmax_loc<<<RR, 128, 0, stream>>>(offaw, ref, ts, loco, ls, awo, as_);
        msda_sample<<<RR, 256, 0, stream>>>(value_b, loco, ls, awo, as_, ts, lsi, samp_b);
        if (pb)
            gemm_mfma<0,1,1,0><<<g2, 256, 0, stream>>>(samp_b, Wpt, bp, pf, pb, 256, 256, nullptr);
        else
            gemm_mfma<0,1,0,0><<<g2, 256, 0, stream>>>(samp_b, Wpt, bp, pf, nullptr, 256, 256, nullptr);
    };

    // Phase 1: video self-attention -> video_b (bf16 LN output)
    pack2<<<n4 / 256, 256, 0, stream>>>(video_src, video_pos, src_b, q_b, n4);
    msda(q_b, src_b, video_ref, video_ts, video_lsi, video_mask,
         loc_tmp, 128, offaw + 128, 256, proj_f, nullptr);
    add_ln<0,1><<<RR, 256, 0, stream>>>(video_src, proj_f, ln1_g, ln1_b, nullptr, video_b);

    // Phase 2: audio self-attention -> audio_b
    pack2<<<n4 / 256, 256, 0, stream>>>(audio_src, audio_pos, src_b, q_b, n4);
    msda(q_b, src_b, audio_ref, audio_ts, audio_lsi, audio_mask,
         loc_tmp, 128, offaw + 128, 256, proj_f, nullptr);
    add_ln<0,1><<<RR, 256, 0, stream>>>(audio_src, proj_f, ln1_g, ln1_b, nullptr, audio_b);

    // Phase 3: vaa = msda(q=audio, src=video) -> a_loc, a_aw; FFN -> out_vaa
    msda(audio_b, video_b, audio_ref, video_ts, video_lsi, video_mask,
         out_aloc, 128, out_aaw, 128, proj_f, proj_b);
    gemm_mfma<1,0,1,0><<<g8, 256, 0, stream>>>(proj_b, W1t, b1, nullptr, hid_b, 1024, 256, nullptr);
    gemm_mfma<0,1,0,0><<<g2, 256, 0, stream>>>(hid_b, W2t, b2, ffnout, nullptr, 256, 1024, nullptr);
    add_ln<1,0><<<RR, 256, 0, stream>>>(proj_f, ffnout, ln2_g, ln2_b, out_vaa, nullptr);

    // Phase 4: aav = msda(q=video, src=audio) -> v_loc, v_aw; FFN -> out_aav
    msda(video_b, audio_b, video_ref, audio_ts, audio_lsi, audio_mask,
         out_vloc, 128, out_vaw, 128, proj_f, proj_b);
    gemm_mfma<1,0,1,0><<<g8, 256, 0, stream>>>(proj_b, W1t, b1, nullptr, hid_b, 1024, 256, nullptr);
    gemm_mfma<0,1,0,0><<<g2, 256, 0, stream>>>(hid_b, W2t, b2, ffnout, nullptr, 256, 1024, nullptr);
    add_ln<1,0><<<RR, 256, 0, stream>>>(proj_f, ffnout, ln2_g, ln2_b, out_aav, nullptr);
}

// Round 3
// 634.262 us; speedup vs baseline: 3.7963x; 2.2314x over previous
//
#include <hip/hip_runtime.h>
#include <hip/hip_bf16.h>
#include <cstdint>

#define BB 8
#define SS 3840
#define RR (BB*SS)      // 30720 rows

typedef short s16x8 __attribute__((ext_vector_type(8)));
typedef float f32x4 __attribute__((ext_vector_type(4)));

__device__ __forceinline__ ushort f2bf(float f) {
    uint32_t u = __builtin_bit_cast(uint32_t, f);
    u += 0x7FFFu + ((u >> 16) & 1u);
    return (ushort)(u >> 16);
}
__device__ __forceinline__ float bf2f(ushort h) {
    return __builtin_bit_cast(float, (uint32_t)h << 16);
}

#define GLDS16(gp, lp) __builtin_amdgcn_global_load_lds( \
    (const __attribute__((address_space(1))) uint32_t*)(gp), \
    (__attribute__((address_space(3))) uint32_t*)(lp), 16, 0, 0)

// ---------------- weight transpose fp32 -> bf16 : Wt[n][k] = W[k][n] ----------------
__global__ __launch_bounds__(256) void wtrans(const float* __restrict__ W, ushort* __restrict__ Wt,
                                              int K, int N, int noff) {
    int idx = blockIdx.x * 256 + threadIdx.x;
    if (idx >= K * N) return;
    int k = idx / N, n = idx % N;
    Wt[(size_t)(n + noff) * K + k] = f2bf(W[idx]);
}

__global__ void cbias(const float* __restrict__ bo, const float* __restrict__ ba, float* __restrict__ boa) {
    int t = threadIdx.x;
    boa[t] = (t < 128) ? bo[t] : ba[t - 128];
}

// ---------------- pack: src_bf = bf16(src), q_bf = bf16(src+pos) ----------------
__global__ __launch_bounds__(256) void pack2(const float* __restrict__ s, const float* __restrict__ p,
                                             ushort* __restrict__ sb, ushort* __restrict__ qb, int n4) {
    int i = blockIdx.x * 256 + threadIdx.x;
    if (i >= n4) return;
    float4 a = ((const float4*)s)[i];
    float4 b = ((const float4*)p)[i];
    ushort4 u, v;
    u.x = f2bf(a.x); u.y = f2bf(a.y); u.z = f2bf(a.z); u.w = f2bf(a.w);
    v.x = f2bf(a.x + b.x); v.y = f2bf(a.y + b.y); v.z = f2bf(a.z + b.z); v.w = f2bf(a.w + b.w);
    ((ushort4*)sb)[i] = u;
    ((ushort4*)qb)[i] = v;
}

// ---------------- bf16 MFMA GEMM: C[M,N] = A[M,K](bf16) @ Wt[N,K](bf16)^T + bias ----------------
template<int RELU, int WF, int WB, int MASKED>
__global__ __launch_bounds__(256) void gemm_mfma(
    const ushort* __restrict__ A, const ushort* __restrict__ Wt,
    const float* __restrict__ bias,
    float* __restrict__ C, ushort* __restrict__ Cb,
    int N, int K, const unsigned char* __restrict__ mask)
{
    __shared__ ushort As[128 * 64];
    __shared__ ushort Bs[128 * 64];
    const int tid = threadIdx.x;
    const int lane = tid & 63;
    const int wid = tid >> 6;
    const int wr = wid >> 1, wc = wid & 1;
    const int bm = blockIdx.x << 7;
    const int bn = blockIdx.y << 7;
    const int l15 = lane & 15;
    const int l4 = lane >> 4;

    f32x4 acc[4][4] = {};

    for (int k0 = 0; k0 < K; k0 += 64) {
        #pragma unroll
        for (int r = 0; r < 4; ++r) {
            int base = r * 256 + (wid << 6);
            int idx = base + lane;
            int row = idx >> 3, sl = idx & 7;
            int ch = sl ^ (row & 7);
            GLDS16(&A[(size_t)(bm + row) * K + k0 + ch * 8], &As[base << 3]);
        }
        #pragma unroll
        for (int r = 0; r < 4; ++r) {
            int base = r * 256 + (wid << 6);
            int idx = base + lane;
            int col = idx >> 3, sl = idx & 7;
            int ch = sl ^ (col & 7);
            GLDS16(&Wt[(size_t)(bn + col) * K + k0 + ch * 8], &Bs[base << 3]);
        }
        __syncthreads();
        #pragma unroll
        for (int ks = 0; ks < 2; ++ks) {
            s16x8 af[4], bf[4];
            const int k16 = ks * 4 + l4;
            #pragma unroll
            for (int m = 0; m < 4; ++m) {
                int row = (wr << 6) + (m << 4) + l15;
                af[m] = *(const s16x8*)&As[(row << 6) + ((k16 ^ (row & 7)) << 3)];
            }
            #pragma unroll
            for (int n = 0; n < 4; ++n) {
                int col = (wc << 6) + (n << 4) + l15;
                bf[n] = *(const s16x8*)&Bs[(col << 6) + ((k16 ^ (col & 7)) << 3)];
            }
            #pragma unroll
            for (int m = 0; m < 4; ++m)
                #pragma unroll
                for (int n = 0; n < 4; ++n)
                    acc[m][n] = __builtin_amdgcn_mfma_f32_16x16x32_bf16(af[m], bf[n], acc[m][n], 0, 0, 0);
        }
        __syncthreads();
    }

    #pragma unroll
    for (int m = 0; m < 4; ++m) {
        #pragma unroll
        for (int r = 0; r < 4; ++r) {
            const int row = bm + (wr << 6) + (m << 4) + (l4 << 2) + r;
            const bool mz = MASKED ? (mask[row] != 0) : false;
            #pragma unroll
            for (int n = 0; n < 4; ++n) {
                const int col = bn + (wc << 6) + (n << 4) + l15;
                float c = acc[m][n][r] + bias[col];
                if (RELU) c = fmaxf(c, 0.f);
                if (MASKED && mz) c = 0.f;
                if (WF) C[(size_t)row * N + col] = c;
                if (WB) Cb[(size_t)row * N + col] = f2bf(c);
            }
        }
    }
}

// ---------------- softmax(aw over 16 per head) + loc = ref + off/ts ----------------
__global__ __launch_bounds__(128) void softmax_loc(
    const float* __restrict__ offaw,
    const float* __restrict__ ref,
    const int* __restrict__ ts,
    float* __restrict__ loc_out, int loc_stride,
    float* __restrict__ aw_out, int aw_stride)
{
    const int row = blockIdx.x;
    const int t = threadIdx.x;
    const int l = (t >> 2) & 3;
    const float off = offaw[(size_t)row * 256 + t];
    float a = offaw[(size_t)row * 256 + 128 + t];

    float m = a;
    #pragma unroll
    for (int o = 1; o < 16; o <<= 1) m = fmaxf(m, __shfl_xor(m, o));
    float e = __expf(a - m);
    float s = e;
    #pragma unroll
    for (int o = 1; o < 16; o <<= 1) s += __shfl_xor(s, o);

    aw_out[(size_t)row * aw_stride + t] = e / s;
    const float T = (float)ts[l];
    loc_out[(size_t)row * loc_stride + t] = ref[(size_t)row * 4 + l] + off / T;
}

// ---------------- deformable sampling, vectorized ----------------
// block: 256 threads handles 4 rows. Phase 1: 512 point-descriptors into LDS.
// Phase 2: thread = (row_local, head, channel-quad); ushort4 gathers.
struct Desc { float wa, wb; int oa, ob; };   // weights (validity folded), element offsets (×256)

__global__ __launch_bounds__(256) void msda_sample(
    const ushort* __restrict__ value,
    const float* __restrict__ loc, int loc_stride,
    const float* __restrict__ aw, int aw_stride,
    const int* __restrict__ ts, const int* __restrict__ lsi,
    ushort* __restrict__ out)
{
    __shared__ Desc ds[512];
    const int tid = threadIdx.x;
    const int row0 = blockIdx.x << 2;

    #pragma unroll
    for (int d = tid; d < 512; d += 256) {
        const int rl = d >> 7;
        const int rem = d & 127;            // h*16 + l*4 + p
        const int l = (rem >> 2) & 3;
        const int row = row0 + rl;
        const float lc = loc[(size_t)row * loc_stride + rem];
        const float w  = aw[(size_t)row * aw_stride + rem];
        const int T = ts[l];
        const int s0 = lsi[l];
        const float pos = lc * (float)T - 0.5f;
        const float x0 = floorf(pos);
        const float w1 = pos - x0;
        const int i0 = (int)x0;
        const int i1 = i0 + 1;
        const int barow = (row / SS) * SS + s0;
        Desc e;
        e.wa = (i0 >= 0 && i0 < T) ? w * (1.f - w1) : 0.f;
        e.wb = (i1 >= 0 && i1 < T) ? w * w1 : 0.f;
        const int ia = min(max(i0, 0), T - 1);
        const int ib = min(max(i1, 0), T - 1);
        e.oa = (barow + ia) << 8;
        e.ob = (barow + ib) << 8;
        ds[d] = e;
    }
    __syncthreads();

    const int rl = tid >> 6;
    const int h  = (tid >> 3) & 7;
    const int cq = tid & 7;
    const ushort* vb = value + h * 32 + cq * 4;
    const Desc* dd = &ds[rl * 128 + h * 16];

    f32x4 acc0 = {}, acc1 = {};
    #pragma unroll
    for (int lp = 0; lp < 16; lp += 2) {
        const Desc e0 = dd[lp];
        const Desc e1 = dd[lp + 1];
        const uint2 a0 = *(const uint2*)(vb + e0.oa);
        const uint2 b0 = *(const uint2*)(vb + e0.ob);
        const uint2 a1 = *(const uint2*)(vb + e1.oa);
        const uint2 b1 = *(const uint2*)(vb + e1.ob);
        #pragma unroll
        for (int c = 0; c < 2; ++c) {
            const uint32_t ua = (c ? a0.y : a0.x), ub = (c ? b0.y : b0.x);
            const uint32_t va = (c ? a1.y : a1.x), vbw = (c ? b1.y : b1.x);
            acc0[2*c+0] = fmaf(e0.wa, __builtin_bit_cast(float, ua << 16), acc0[2*c+0]);
            acc0[2*c+1] = fmaf(e0.wa, __builtin_bit_cast(float, ua & 0xFFFF0000u), acc0[2*c+1]);
            acc0[2*c+0] = fmaf(e0.wb, __builtin_bit_cast(float, ub << 16), acc0[2*c+0]);
            acc0[2*c+1] = fmaf(e0.wb, __builtin_bit_cast(float, ub & 0xFFFF0000u), acc0[2*c+1]);
            acc1[2*c+0] = fmaf(e1.wa, __builtin_bit_cast(float, va << 16), acc1[2*c+0]);
            acc1[2*c+1] = fmaf(e1.wa, __builtin_bit_cast(float, va & 0xFFFF0000u), acc1[2*c+1]);
            acc1[2*c+0] = fmaf(e1.wb, __builtin_bit_cast(float, vbw << 16), acc1[2*c+0]);
            acc1[2*c+1] = fmaf(e1.wb, __builtin_bit_cast(float, vbw & 0xFFFF0000u), acc1[2*c+1]);
        }
    }
    ushort4 o;
    o.x = f2bf(acc0[0] + acc1[0]);
    o.y = f2bf(acc0[1] + acc1[1]);
    o.z = f2bf(acc0[2] + acc1[2]);
    o.w = f2bf(acc0[3] + acc1[3]);
    *(ushort4*)&out[((size_t)(row0 + rl)) * 256 + h * 32 + cq * 4] = o;
}

// ---------------- residual add + layernorm (dual-dtype output) ----------------
template<int WF, int WB>
__global__ __launch_bounds__(256) void add_ln(
    const float* __restrict__ a, const float* __restrict__ b,
    const float* __restrict__ g, const float* __restrict__ beta,
    float* __restrict__ of, ushort* __restrict__ ob)
{
    __shared__ float red[8];
    const int row = blockIdx.x;
    const int t = threadIdx.x;
    const float x = a[(size_t)row * 256 + t] + b[(size_t)row * 256 + t];
    float s1 = x, s2 = x * x;
    #pragma unroll
    for (int o = 32; o > 0; o >>= 1) {
        s1 += __shfl_xor(s1, o);
        s2 += __shfl_xor(s2, o);
    }
    const int wid = t >> 6;
    if ((t & 63) == 0) { red[wid] = s1; red[4 + wid] = s2; }
    __syncthreads();
    const float S1 = red[0] + red[1] + red[2] + red[3];
    const float S2 = red[4] + red[5] + red[6] + red[7];
    const float m = S1 * (1.f / 256.f);
    float v = S2 * (1.f / 256.f) - m * m;
    v = fmaxf(v, 0.f);
    const float r = rsqrtf(v + 1e-5f);
    const float y = (x - m) * r * g[t] + beta[t];
    if (WF) of[(size_t)row * 256 + t] = y;
    if (WB) ob[(size_t)row * 256 + t] = f2bf(y);
}

extern "C" void kernel_launch(void* const* d_in, const int* in_sizes, int n_in,
                              void* d_out, int out_size, void* d_ws, size_t ws_size,
                              hipStream_t stream) {
    const float* video_src = (const float*)d_in[0];
    const float* audio_src = (const float*)d_in[1];
    const float* video_pos = (const float*)d_in[2];
    const float* audio_pos = (const float*)d_in[3];
    const float* video_ref = (const float*)d_in[4];
    const float* audio_ref = (const float*)d_in[5];
    const int*   video_ts  = (const int*)d_in[6];
    const int*   video_lsi = (const int*)d_in[7];
    const unsigned char* video_mask = (const unsigned char*)d_in[8];
    const int*   audio_ts  = (const int*)d_in[9];
    const int*   audio_lsi = (const int*)d_in[10];
    const unsigned char* audio_mask = (const unsigned char*)d_in[11];
    const float* Wv = (const float*)d_in[12];
    const float* bv = (const float*)d_in[13];
    const float* Wo = (const float*)d_in[14];
    const float* bo = (const float*)d_in[15];
    const float* Wa = (const float*)d_in[16];
    const float* ba = (const float*)d_in[17];
    const float* Wp = (const float*)d_in[18];
    const float* bp = (const float*)d_in[19];
    const float* ln1_g = (const float*)d_in[20];
    const float* ln1_b = (const float*)d_in[21];
    const float* W1 = (const float*)d_in[22];
    const float* b1 = (const float*)d_in[23];
    const float* W2 = (const float*)d_in[24];
    const float* b2 = (const float*)d_in[25];
    const float* ln2_g = (const float*)d_in[26];
    const float* ln2_b = (const float*)d_in[27];

    float* out = (float*)d_out;
    const size_t n = (size_t)RR * 256;
    float* out_aav  = out;
    float* out_vaa  = out + n;
    float* out_vloc = out + 2 * n;
    float* out_vaw  = out + 2 * n + n / 2;
    float* out_aloc = out + 3 * n;
    float* out_aaw  = out + 3 * n + n / 2;

    char* base = (char*)d_ws;
    ushort* video_b = (ushort*)(base + 0 * n);
    ushort* audio_b = (ushort*)(base + 2 * n);
    ushort* src_b   = (ushort*)(base + 4 * n);
    ushort* q_b     = (ushort*)(base + 6 * n);
    float*  loc_tmp = (float*) (base + 8 * n);
    ushort* value_b = (ushort*)(base + 10 * n);
    float*  offaw   = (float*) (base + 12 * n);
    ushort* samp_b  = (ushort*)(base + 16 * n);
    float*  proj_f  = (float*) (base + 18 * n);
    ushort* proj_b  = (ushort*)(base + 22 * n);
    ushort* hid_b   = (ushort*)(base + 4 * n);
    float*  ffnout  = (float*) (base + 12 * n);
    ushort* Wvt  = (ushort*)(base + 24 * n);
    ushort* Woat = Wvt + 65536;
    ushort* Wpt  = Woat + 65536;
    ushort* W1t  = Wpt + 65536;
    ushort* W2t  = W1t + 262144;
    float*  boa  = (float*)(W2t + 262144);

    wtrans<<<256, 256, 0, stream>>>(Wv, Wvt, 256, 256, 0);
    wtrans<<<128, 256, 0, stream>>>(Wo, Woat, 256, 128, 0);
    wtrans<<<128, 256, 0, stream>>>(Wa, Woat, 256, 128, 128);
    wtrans<<<256, 256, 0, stream>>>(Wp, Wpt, 256, 256, 0);
    wtrans<<<1024, 256, 0, stream>>>(W1, W1t, 256, 1024, 0);
    wtrans<<<1024, 256, 0, stream>>>(W2, W2t, 1024, 256, 0);
    cbias<<<1, 256, 0, stream>>>(bo, ba, boa);

    const int n4 = (int)(n / 4);
    const dim3 g2(240, 2), g8(240, 8);

    auto msda = [&](const ushort* qb, const ushort* srcb, const float* ref,
                    const int* ts, const int* lsi, const unsigned char* mk,
                    float* loco, int ls, float* awo, int as_,
                    float* pf, ushort* pb) {
        gemm_mfma<0,0,1,1><<<g2, 256, 0, stream>>>(srcb, Wvt, bv, nullptr, value_b, 256, 256, mk);
        gemm_mfma<0,1,0,0><<<g2, 256, 0, stream>>>(qb, Woat, boa, offaw, nullptr, 256, 256, nullptr);
        softmax_loc<<<RR, 128, 0, stream>>>(offaw, ref, ts, loco, ls, awo, as_);
        msda_sample<<<RR/4, 256, 0, stream>>>(value_b, loco, ls, awo, as_, ts, lsi, samp_b);
        if (pb)
            gemm_mfma<0,1,1,0><<<g2, 256, 0, stream>>>(samp_b, Wpt, bp, pf, pb, 256, 256, nullptr);
        else
            gemm_mfma<0,1,0,0><<<g2, 256, 0, stream>>>(samp_b, Wpt, bp, pf, nullptr, 256, 256, nullptr);
    };

    // Phase 1: video self-attention
    pack2<<<n4 / 256, 256, 0, stream>>>(video_src, video_pos, src_b, q_b, n4);
    msda(q_b, src_b, video_ref, video_ts, video_lsi, video_mask,
         loc_tmp, 128, offaw + 128, 256, proj_f, nullptr);
    add_ln<0,1><<<RR, 256, 0, stream>>>(video_src, proj_f, ln1_g, ln1_b, nullptr, video_b);

    // Phase 2: audio self-attention
    pack2<<<n4 / 256, 256, 0, stream>>>(audio_src, audio_pos, src_b, q_b, n4);
    msda(q_b, src_b, audio_ref, audio_ts, audio_lsi, audio_mask,
         loc_tmp, 128, offaw + 128, 256, proj_f, nullptr);
    add_ln<0,1><<<RR, 256, 0, stream>>>(audio_src, proj_f, ln1_g, ln1_b, nullptr, audio_b);

    // Phase 3: vaa
    msda(audio_b, video_b, audio_ref, video_ts, video_lsi, video_mask,
         out_aloc, 128, out_aaw, 128, proj_f, proj_b);
    gemm_mfma<1,0,1,0><<<g8, 256, 0, stream>>>(proj_b, W1t, b1, nullptr, hid_b, 1024, 256, nullptr);
    gemm_mfma<0,1,0,0><<<g2, 256, 0, stream>>>(hid_b, W2t, b2, ffnout, nullptr, 256, 1024, nullptr);
    add_ln<1,0><<<RR, 256, 0, stream>>>(proj_f, ffnout, ln2_g, ln2_b, out_vaa, nullptr);

    // Phase 4: aav
    msda(video_b, audio_b, video_ref, audio_ts, audio_lsi, audio_mask,
         out_vloc, 128, out_vaw, 128, proj_f, proj_b);
    gemm_mfma<1,0,1,0><<<g8, 256, 0, stream>>>(proj_b, W1t, b1, nullptr, hid_b, 1024, 256, nullptr);
    gemm_mfma<0,1,0,0><<<g2, 256, 0, stream>>>(hid_b, W2t, b2, ffnout, nullptr, 256, 1024, nullptr);
    add_ln<1,0><<<RR, 256, 0, stream>>>(proj_f, ffnout, ln2_g, ln2_b, out_aav, nullptr);
}

// Round 5
// 489.462 us; speedup vs baseline: 4.9194x; 1.2958x over previous
//
#include <hip/hip_runtime.h>
#include <hip/hip_bf16.h>
#include <cstdint>

#define BB 8
#define SS 3840
#define RR (BB*SS)                 // 30720 rows per modality
#define NHALF ((size_t)RR * 256)   // elems per half plane

typedef short s16x8 __attribute__((ext_vector_type(8)));
typedef float f32x4 __attribute__((ext_vector_type(4)));

__device__ __forceinline__ ushort f2bf(float f) {
    uint32_t u = __builtin_bit_cast(uint32_t, f);
    u += 0x7FFFu + ((u >> 16) & 1u);
    return (ushort)(u >> 16);
}
__device__ __forceinline__ float bf2f(ushort h) {
    return __builtin_bit_cast(float, (uint32_t)h << 16);
}

#define GLDS16(gp, lp) __builtin_amdgcn_global_load_lds( \
    (const __attribute__((address_space(1))) uint32_t*)(gp), \
    (__attribute__((address_space(3))) uint32_t*)(lp), 16, 0, 0)

// ---------------- all weight prep in one kernel ----------------
// Segment sizes: Wv 65536, Wo 32768, Wa 32768, Wp 65536, W1 262144, W2 262144, boa 256.
__global__ __launch_bounds__(256) void wtrans_all(
    const float* __restrict__ Wv, const float* __restrict__ Wo,
    const float* __restrict__ Wa, const float* __restrict__ Wp,
    const float* __restrict__ W1, const float* __restrict__ W2,
    const float* __restrict__ bo, const float* __restrict__ ba,
    ushort* __restrict__ Wvt, ushort* __restrict__ Woat, ushort* __restrict__ Wpt,
    ushort* __restrict__ W1t, ushort* __restrict__ W2t, float* __restrict__ boa)
{
    int e = blockIdx.x * 256 + threadIdx.x;
    if (e < 65536)       { int k = e >> 8, n = e & 255;  Wvt[n * 256 + k] = f2bf(Wv[e]); }
    else if (e < 98304)  { int i = e - 65536;  int k = i >> 7, n = i & 127;  Woat[n * 256 + k] = f2bf(Wo[i]); }
    else if (e < 131072) { int i = e - 98304;  int k = i >> 7, n = i & 127;  Woat[(n + 128) * 256 + k] = f2bf(Wa[i]); }
    else if (e < 196608) { int i = e - 131072; int k = i >> 8, n = i & 255;  Wpt[n * 256 + k] = f2bf(Wp[i]); }
    else if (e < 458752) { int i = e - 196608; int k = i >> 10, n = i & 1023; W1t[n * 256 + k] = f2bf(W1[i]); }
    else if (e < 720896) { int i = e - 458752; int k = i >> 8, n = i & 255;  W2t[(size_t)n * 1024 + k] = f2bf(W2[i]); }
    else if (e < 721152) { int t = e - 720896; boa[t] = (t < 128) ? bo[t] : ba[t - 128]; }
}

// ---------------- pack both modalities: src_bf, q_bf = bf16(src), bf16(src+pos) ----------------
__global__ __launch_bounds__(256) void pack2_cat(
    const float* __restrict__ vs, const float* __restrict__ as_,
    const float* __restrict__ vp, const float* __restrict__ ap,
    ushort* __restrict__ sb, ushort* __restrict__ qb)
{
    const int n4 = (int)(NHALF / 4);
    int i = blockIdx.x * 256 + threadIdx.x;
    int j = (i < n4) ? i : i - n4;
    const float4* s4 = (const float4*)((i < n4) ? vs : as_);
    const float4* p4 = (const float4*)((i < n4) ? vp : ap);
    float4 a = s4[j];
    float4 b = p4[j];
    ushort4 u, v;
    u.x = f2bf(a.x); u.y = f2bf(a.y); u.z = f2bf(a.z); u.w = f2bf(a.w);
    v.x = f2bf(a.x + b.x); v.y = f2bf(a.y + b.y); v.z = f2bf(a.z + b.z); v.w = f2bf(a.w + b.w);
    ((ushort4*)sb)[i] = u;
    ((ushort4*)qb)[i] = v;
}

// ---------------- fused value+offaw GEMM (batched over both halves) ----------------
// grid (480, 4): y>>1 = job (0 value, 1 offaw); y&1 = N-half (bn 0/128). K=N=256.
// value job: head-major bf16 out + mask. offaw job: bn==0 -> loc epilogue, bn==128 -> softmax(aw).
__global__ __launch_bounds__(256) void gemm_fused(
    const ushort* __restrict__ Av0, const ushort* __restrict__ Av1,
    const ushort* __restrict__ Ao0, const ushort* __restrict__ Ao1,
    const ushort* __restrict__ WvT, const ushort* __restrict__ WoT,
    const float* __restrict__ bv, const float* __restrict__ boa,
    ushort* __restrict__ val_out,
    float* __restrict__ loc0, float* __restrict__ loc1,
    float* __restrict__ aw0, float* __restrict__ aw1,
    const float* __restrict__ ref0, const float* __restrict__ ref1,
    const int* __restrict__ ts0, const int* __restrict__ ts1,
    const unsigned char* __restrict__ mask0, const unsigned char* __restrict__ mask1)
{
    __shared__ ushort As[128 * 64];
    __shared__ ushort Bs[128 * 64];
    const int tid = threadIdx.x;
    const int lane = tid & 63;
    const int wid = tid >> 6;
    const int wr = wid >> 1, wc = wid & 1;
    const int job = blockIdx.y >> 1;
    const int bn = (blockIdx.y & 1) << 7;
    const int bm = blockIdx.x << 7;
    const int half = bm >= RR;
    const int bmL = half ? bm - RR : bm;
    const int l15 = lane & 15;
    const int l4 = lane >> 4;

    const ushort* A = job ? (half ? Ao1 : Ao0) : (half ? Av1 : Av0);
    const ushort* Wt = job ? WoT : WvT;
    A += (size_t)bmL * 256;

    f32x4 acc[4][4] = {};

    for (int k0 = 0; k0 < 256; k0 += 64) {
        #pragma unroll
        for (int r = 0; r < 4; ++r) {
            int base = r * 256 + (wid << 6);
            int idx = base + lane;
            int row = idx >> 3, sl = idx & 7;
            int ch = sl ^ (row & 7);
            GLDS16(&A[(size_t)row * 256 + k0 + ch * 8], &As[base << 3]);
        }
        #pragma unroll
        for (int r = 0; r < 4; ++r) {
            int base = r * 256 + (wid << 6);
            int idx = base + lane;
            int col = idx >> 3, sl = idx & 7;
            int ch = sl ^ (col & 7);
            GLDS16(&Wt[(size_t)(bn + col) * 256 + k0 + ch * 8], &Bs[base << 3]);
        }
        __syncthreads();
        #pragma unroll
        for (int ks = 0; ks < 2; ++ks) {
            s16x8 af[4], bf[4];
            const int k16 = ks * 4 + l4;
            #pragma unroll
            for (int m = 0; m < 4; ++m) {
                int row = (wr << 6) + (m << 4) + l15;
                af[m] = *(const s16x8*)&As[(row << 6) + ((k16 ^ (row & 7)) << 3)];
            }
            #pragma unroll
            for (int n = 0; n < 4; ++n) {
                int col = (wc << 6) + (n << 4) + l15;
                bf[n] = *(const s16x8*)&Bs[(col << 6) + ((k16 ^ (col & 7)) << 3)];
            }
            #pragma unroll
            for (int m = 0; m < 4; ++m)
                #pragma unroll
                for (int n = 0; n < 4; ++n)
                    acc[m][n] = __builtin_amdgcn_mfma_f32_16x16x32_bf16(af[m], bf[n], acc[m][n], 0, 0, 0);
        }
        __syncthreads();
    }

    const int l4r = l4 << 2;
    if (job == 0) {
        // value: head-major [half][b][h][s][32] bf16, row-masked
        const unsigned char* mk = half ? mask1 : mask0;
        ushort* vo = val_out + (size_t)half * NHALF;
        #pragma unroll
        for (int m = 0; m < 4; ++m) {
            #pragma unroll
            for (int r = 0; r < 4; ++r) {
                const int rowL = bmL + (wr << 6) + (m << 4) + l4r + r;
                const int b = rowL / SS;
                const int s = rowL - b * SS;
                const float mz = mk[rowL] ? 0.f : 1.f;
                const size_t rb = ((size_t)(b * 8) * SS + s) * 32;
                #pragma unroll
                for (int n = 0; n < 4; ++n) {
                    const int col = bn + (wc << 6) + (n << 4) + l15;
                    const int h = col >> 5, d = col & 31;
                    vo[rb + (size_t)h * (SS * 32) + d] = f2bf((acc[m][n][r] + bv[col]) * mz);
                }
            }
        }
    } else if (bn == 0) {
        // off -> loc = ref + off/ts
        const float* rf = half ? ref1 : ref0;
        const int* tsp = half ? ts1 : ts0;
        const int l = l15 >> 2;
        const float T = (float)tsp[l];
        float* lo = half ? loc1 : loc0;
        #pragma unroll
        for (int m = 0; m < 4; ++m) {
            #pragma unroll
            for (int r = 0; r < 4; ++r) {
                const int rowL = bmL + (wr << 6) + (m << 4) + l4r + r;
                const float refv = rf[(size_t)rowL * 4 + l];
                #pragma unroll
                for (int n = 0; n < 4; ++n) {
                    const int cc = (wc << 6) + (n << 4) + l15;
                    lo[(size_t)rowL * 128 + cc] = refv + (acc[m][n][r] + boa[cc]) / T;
                }
            }
        }
    } else {
        // aw -> softmax over 16 cols per head (16-lane group == head group)
        float* ao = half ? aw1 : aw0;
        #pragma unroll
        for (int m = 0; m < 4; ++m) {
            #pragma unroll
            for (int r = 0; r < 4; ++r) {
                const int rowL = bmL + (wr << 6) + (m << 4) + l4r + r;
                #pragma unroll
                for (int n = 0; n < 4; ++n) {
                    const int cc = (wc << 6) + (n << 4) + l15;
                    float c = acc[m][n][r] + boa[128 + cc];
                    float mx = c;
                    #pragma unroll
                    for (int o = 1; o < 16; o <<= 1) mx = fmaxf(mx, __shfl_xor(mx, o));
                    float e = __expf(c - mx);
                    float sm = e;
                    #pragma unroll
                    for (int o = 1; o < 16; o <<= 1) sm += __shfl_xor(sm, o);
                    ao[(size_t)rowL * 128 + cc] = e / sm;
                }
            }
        }
    }
}

// ---------------- generic bf16 MFMA GEMM (proj / FFN) ----------------
template<int RELU, int WF, int WB>
__global__ __launch_bounds__(256) void gemm_mfma(
    const ushort* __restrict__ A, const ushort* __restrict__ Wt,
    const float* __restrict__ bias,
    float* __restrict__ C, ushort* __restrict__ Cb, int N, int K)
{
    __shared__ ushort As[128 * 64];
    __shared__ ushort Bs[128 * 64];
    const int tid = threadIdx.x;
    const int lane = tid & 63;
    const int wid = tid >> 6;
    const int wr = wid >> 1, wc = wid & 1;
    const int bm = blockIdx.x << 7;
    const int bn = blockIdx.y << 7;
    const int l15 = lane & 15;
    const int l4 = lane >> 4;

    f32x4 acc[4][4] = {};

    for (int k0 = 0; k0 < K; k0 += 64) {
        #pragma unroll
        for (int r = 0; r < 4; ++r) {
            int base = r * 256 + (wid << 6);
            int idx = base + lane;
            int row = idx >> 3, sl = idx & 7;
            int ch = sl ^ (row & 7);
            GLDS16(&A[(size_t)(bm + row) * K + k0 + ch * 8], &As[base << 3]);
        }
        #pragma unroll
        for (int r = 0; r < 4; ++r) {
            int base = r * 256 + (wid << 6);
            int idx = base + lane;
            int col = idx >> 3, sl = idx & 7;
            int ch = sl ^ (col & 7);
            GLDS16(&Wt[(size_t)(bn + col) * K + k0 + ch * 8], &Bs[base << 3]);
        }
        __syncthreads();
        #pragma unroll
        for (int ks = 0; ks < 2; ++ks) {
            s16x8 af[4], bf[4];
            const int k16 = ks * 4 + l4;
            #pragma unroll
            for (int m = 0; m < 4; ++m) {
                int row = (wr << 6) + (m << 4) + l15;
                af[m] = *(const s16x8*)&As[(row << 6) + ((k16 ^ (row & 7)) << 3)];
            }
            #pragma unroll
            for (int n = 0; n < 4; ++n) {
                int col = (wc << 6) + (n << 4) + l15;
                bf[n] = *(const s16x8*)&Bs[(col << 6) + ((k16 ^ (col & 7)) << 3)];
            }
            #pragma unroll
            for (int m = 0; m < 4; ++m)
                #pragma unroll
                for (int n = 0; n < 4; ++n)
                    acc[m][n] = __builtin_amdgcn_mfma_f32_16x16x32_bf16(af[m], bf[n], acc[m][n], 0, 0, 0);
        }
        __syncthreads();
    }

    #pragma unroll
    for (int m = 0; m < 4; ++m) {
        #pragma unroll
        for (int r = 0; r < 4; ++r) {
            const int row = bm + (wr << 6) + (m << 4) + (l4 << 2) + r;
            #pragma unroll
            for (int n = 0; n < 4; ++n) {
                const int col = bn + (wc << 6) + (n << 4) + l15;
                float c = acc[m][n][r] + bias[col];
                if (RELU) c = fmaxf(c, 0.f);
                if (WF) C[(size_t)row * N + col] = c;
                if (WB) Cb[(size_t)row * N + col] = f2bf(c);
            }
        }
    }
}

// ---------------- deformable sampling (head-major value, batched halves) ----------------
struct Desc { float wa, wb; int oa, ob; };

__global__ __launch_bounds__(256) void msda_sample(
    const ushort* __restrict__ value,
    const float* __restrict__ l0, const float* __restrict__ l1,
    const float* __restrict__ a0, const float* __restrict__ a1,
    const int* __restrict__ ts0, const int* __restrict__ lsi0,
    const int* __restrict__ ts1, const int* __restrict__ lsi1,
    ushort* __restrict__ out)
{
    __shared__ Desc ds[512];
    const int tid = threadIdx.x;
    const int row0 = blockIdx.x << 2;
    const int half = row0 >= RR;
    const int rowL0 = half ? row0 - RR : row0;
    const float* loc = half ? l1 : l0;
    const float* aw  = half ? a1 : a0;
    const int* ts  = half ? ts1 : ts0;
    const int* lsi = half ? lsi1 : lsi0;
    const ushort* val = value + (size_t)half * NHALF;

    #pragma unroll
    for (int d = tid; d < 512; d += 256) {
        const int rl = d >> 7;
        const int rem = d & 127;           // h*16 + l*4 + p
        const int l = (rem >> 2) & 3;
        const int h = rem >> 4;
        const int rowL = rowL0 + rl;
        const float lc = loc[(size_t)rowL * 128 + rem];
        const float w  = aw[(size_t)rowL * 128 + rem];
        const int T = ts[l];
        const int s0 = lsi[l];
        const int b = rowL / SS;
        const float pos = lc * (float)T - 0.5f;
        const float x0 = floorf(pos);
        const float w1 = pos - x0;
        const int i0 = (int)x0;
        const int i1 = i0 + 1;
        const int base = (b * 8 + h) * SS + s0;
        Desc e;
        e.wa = (i0 >= 0 && i0 < T) ? w * (1.f - w1) : 0.f;
        e.wb = (i1 >= 0 && i1 < T) ? w * w1 : 0.f;
        const int ia = min(max(i0, 0), T - 1);
        const int ib = min(max(i1, 0), T - 1);
        e.oa = (base + ia) << 5;
        e.ob = (base + ib) << 5;
        ds[d] = e;
    }
    __syncthreads();

    const int rl = tid >> 6;
    const int h  = (tid >> 3) & 7;
    const int cq = tid & 7;
    const ushort* vb = val + cq * 4;
    const Desc* dd = &ds[rl * 128 + h * 16];

    f32x4 acc0 = {}, acc1 = {};
    #pragma unroll
    for (int lp = 0; lp < 16; lp += 2) {
        const Desc e0 = dd[lp];
        const Desc e1 = dd[lp + 1];
        const uint2 A0 = *(const uint2*)(vb + e0.oa);
        const uint2 B0 = *(const uint2*)(vb + e0.ob);
        const uint2 A1 = *(const uint2*)(vb + e1.oa);
        const uint2 B1 = *(const uint2*)(vb + e1.ob);
        #pragma unroll
        for (int c = 0; c < 2; ++c) {
            const uint32_t ua = (c ? A0.y : A0.x), ub = (c ? B0.y : B0.x);
            const uint32_t va = (c ? A1.y : A1.x), vw = (c ? B1.y : B1.x);
            acc0[2*c+0] = fmaf(e0.wa, __builtin_bit_cast(float, ua << 16), acc0[2*c+0]);
            acc0[2*c+1] = fmaf(e0.wa, __builtin_bit_cast(float, ua & 0xFFFF0000u), acc0[2*c+1]);
            acc0[2*c+0] = fmaf(e0.wb, __builtin_bit_cast(float, ub << 16), acc0[2*c+0]);
            acc0[2*c+1] = fmaf(e0.wb, __builtin_bit_cast(float, ub & 0xFFFF0000u), acc0[2*c+1]);
            acc1[2*c+0] = fmaf(e1.wa, __builtin_bit_cast(float, va << 16), acc1[2*c+0]);
            acc1[2*c+1] = fmaf(e1.wa, __builtin_bit_cast(float, va & 0xFFFF0000u), acc1[2*c+1]);
            acc1[2*c+0] = fmaf(e1.wb, __builtin_bit_cast(float, vw << 16), acc1[2*c+0]);
            acc1[2*c+1] = fmaf(e1.wb, __builtin_bit_cast(float, vw & 0xFFFF0000u), acc1[2*c+1]);
        }
    }
    ushort4 o;
    o.x = f2bf(acc0[0] + acc1[0]);
    o.y = f2bf(acc0[1] + acc1[1]);
    o.z = f2bf(acc0[2] + acc1[2]);
    o.w = f2bf(acc0[3] + acc1[3]);
    *(ushort4*)&out[(size_t)(row0 + rl) * 256 + h * 32 + cq * 4] = o;
}

// ---------------- residual + layernorm, 4 rows/block, 1 wave/row ----------------
// MODE 0 (post-attn): x = f32 residual (a0/a1 select) + bf16 proj; out bf16 -> ob (cat).
// MODE 1 (post-FFN):  x = bf16 proj + f32 ffnout; out f32 -> of0/of1 select.
template<int MODE>
__global__ __launch_bounds__(256) void add_ln4(
    const float* __restrict__ a0, const float* __restrict__ a1,
    const ushort* __restrict__ pb, const float* __restrict__ bf,
    const float* __restrict__ g, const float* __restrict__ be,
    ushort* __restrict__ ob, float* __restrict__ of0, float* __restrict__ of1)
{
    const int tid = threadIdx.x;
    const int row = (blockIdx.x << 2) + (tid >> 6);
    const int lane = tid & 63;
    const int half = row >= RR;
    const int rowL = half ? row - RR : row;

    ushort4 pv = ((const ushort4*)(pb + (size_t)row * 256))[lane];
    float px = bf2f(pv.x), py = bf2f(pv.y), pz = bf2f(pv.z), pw = bf2f(pv.w);
    float4 x;
    if (MODE == 0) {
        const float* a = half ? a1 : a0;
        float4 av = ((const float4*)(a + (size_t)rowL * 256))[lane];
        x.x = av.x + px; x.y = av.y + py; x.z = av.z + pz; x.w = av.w + pw;
    } else {
        float4 fv = ((const float4*)(bf + (size_t)row * 256))[lane];
        x.x = fv.x + px; x.y = fv.y + py; x.z = fv.z + pz; x.w = fv.w + pw;
    }
    float s1 = x.x + x.y + x.z + x.w;
    float s2 = x.x * x.x + x.y * x.y + x.z * x.z + x.w * x.w;
    #pragma unroll
    for (int o = 32; o > 0; o >>= 1) {
        s1 += __shfl_xor(s1, o);
        s2 += __shfl_xor(s2, o);
    }
    const float m = s1 * (1.f / 256.f);
    float v = s2 * (1.f / 256.f) - m * m;
    v = fmaxf(v, 0.f);
    const float r = rsqrtf(v + 1e-5f);
    float4 g4 = ((const float4*)g)[lane];
    float4 b4 = ((const float4*)be)[lane];
    float4 y;
    y.x = (x.x - m) * r * g4.x + b4.x;
    y.y = (x.y - m) * r * g4.y + b4.y;
    y.z = (x.z - m) * r * g4.z + b4.z;
    y.w = (x.w - m) * r * g4.w + b4.w;
    if (MODE == 0) {
        ushort4 o;
        o.x = f2bf(y.x); o.y = f2bf(y.y); o.z = f2bf(y.z); o.w = f2bf(y.w);
        ((ushort4*)(ob + (size_t)row * 256))[lane] = o;
    } else {
        ((float4*)((half ? of1 : of0) + (size_t)rowL * 256))[lane] = y;
    }
}

extern "C" void kernel_launch(void* const* d_in, const int* in_sizes, int n_in,
                              void* d_out, int out_size, void* d_ws, size_t ws_size,
                              hipStream_t stream) {
    const float* video_src = (const float*)d_in[0];
    const float* audio_src = (const float*)d_in[1];
    const float* video_pos = (const float*)d_in[2];
    const float* audio_pos = (const float*)d_in[3];
    const float* video_ref = (const float*)d_in[4];
    const float* audio_ref = (const float*)d_in[5];
    const int*   video_ts  = (const int*)d_in[6];
    const int*   video_lsi = (const int*)d_in[7];
    const unsigned char* video_mask = (const unsigned char*)d_in[8];
    const int*   audio_ts  = (const int*)d_in[9];
    const int*   audio_lsi = (const int*)d_in[10];
    const unsigned char* audio_mask = (const unsigned char*)d_in[11];
    const float* Wv = (const float*)d_in[12];
    const float* bv = (const float*)d_in[13];
    const float* Wo = (const float*)d_in[14];
    const float* bo = (const float*)d_in[15];
    const float* Wa = (const float*)d_in[16];
    const float* ba = (const float*)d_in[17];
    const float* Wp = (const float*)d_in[18];
    const float* bp = (const float*)d_in[19];
    const float* ln1_g = (const float*)d_in[20];
    const float* ln1_b = (const float*)d_in[21];
    const float* W1 = (const float*)d_in[22];
    const float* b1 = (const float*)d_in[23];
    const float* W2 = (const float*)d_in[24];
    const float* b2 = (const float*)d_in[25];
    const float* ln2_g = (const float*)d_in[26];
    const float* ln2_b = (const float*)d_in[27];

    float* out = (float*)d_out;
    const size_t n = NHALF;
    float* out_aav  = out;
    float* out_vaa  = out + n;
    float* out_vloc = out + 2 * n;
    float* out_vaw  = out + 2 * n + n / 2;
    float* out_aloc = out + 3 * n;
    float* out_aaw  = out + 3 * n + n / 2;

    // workspace: UB = one bf16 plane (RR x 256) bytes = 15,728,640. Total 14UB + weights ~ 222 MB.
    const size_t UB = NHALF * 2;
    char* base = (char*)d_ws;
    ushort* src_cat   = (ushort*)(base + 0 * UB);   // P12 [0,2U)
    ushort* q_cat     = (ushort*)(base + 2 * UB);   // P12 [2U,4U)
    float*  loc_tmp   = (float*) (base + 4 * UB);   // P12 [4U,6U)
    float*  aw_tmp    = (float*) (base + 6 * UB);   // P12 [6U,8U)
    ushort* hid       = (ushort*)(base + 0 * UB);   // P34 [0,8U)
    ushort* value_cat = (ushort*)(base + 8 * UB);   // [8U,10U)
    ushort* samp_cat  = (ushort*)(base + 10 * UB);  // [10U,12U)
    float*  ffnout    = (float*) (base + 8 * UB);   // P34 [8U,12U) after sampling
    ushort* vb_cat    = (ushort*)(base + 12 * UB);  // [12U,14U)
    ushort* proj_b34  = (ushort*)(base + 12 * UB);  // overwrites vb after P34 gemm_fused
    ushort* proj_b12  = (ushort*)(base + 4 * UB);   // overwrites loc_tmp after P12 sample
    ushort* Wvt  = (ushort*)(base + 14 * UB);
    ushort* Woat = Wvt + 65536;
    ushort* Wpt  = Woat + 65536;
    ushort* W1t  = Wpt + 65536;
    ushort* W2t  = W1t + 262144;
    float*  boa  = (float*)(W2t + 262144);

    wtrans_all<<<2817, 256, 0, stream>>>(Wv, Wo, Wa, Wp, W1, W2, bo, ba,
                                         Wvt, Woat, Wpt, W1t, W2t, boa);
    pack2_cat<<<15360, 256, 0, stream>>>(video_src, audio_src, video_pos, audio_pos,
                                         src_cat, q_cat);

    // ---- Phase 1+2: self-attention (video rows [0,RR), audio rows [RR,2RR)) ----
    gemm_fused<<<dim3(480, 4), 256, 0, stream>>>(
        src_cat, src_cat + NHALF, q_cat, q_cat + NHALF,
        Wvt, Woat, bv, boa, value_cat,
        loc_tmp, loc_tmp + (size_t)RR * 128, aw_tmp, aw_tmp + (size_t)RR * 128,
        video_ref, audio_ref, video_ts, audio_ts, video_mask, audio_mask);
    msda_sample<<<15360, 256, 0, stream>>>(
        value_cat, loc_tmp, loc_tmp + (size_t)RR * 128, aw_tmp, aw_tmp + (size_t)RR * 128,
        video_ts, video_lsi, audio_ts, audio_lsi, samp_cat);
    gemm_mfma<0,0,1><<<dim3(480, 2), 256, 0, stream>>>(samp_cat, Wpt, bp, nullptr, proj_b12, 256, 256);
    add_ln4<0><<<15360, 256, 0, stream>>>(video_src, audio_src, proj_b12, nullptr,
                                          ln1_g, ln1_b, vb_cat, nullptr, nullptr);

    // ---- Phase 3+4: cross-attention + FFN
    // half0 = call3 (q=audio, src=video) -> a_loc/a_aw, vaa; half1 = call4 -> v_loc/v_aw, aav
    gemm_fused<<<dim3(480, 4), 256, 0, stream>>>(
        vb_cat, vb_cat + NHALF,            // value A: [video_b ; audio_b]
        vb_cat + NHALF, vb_cat,            // offaw A: [audio_b ; video_b]
        Wvt, Woat, bv, boa, value_cat,
        out_aloc, out_vloc, out_aaw, out_vaw,
        audio_ref, video_ref, video_ts, audio_ts, video_mask, audio_mask);
    msda_sample<<<15360, 256, 0, stream>>>(
        value_cat, out_aloc, out_vloc, out_aaw, out_vaw,
        video_ts, video_lsi, audio_ts, audio_lsi, samp_cat);
    gemm_mfma<0,0,1><<<dim3(480, 2), 256, 0, stream>>>(samp_cat, Wpt, bp, nullptr, proj_b34, 256, 256);
    gemm_mfma<1,0,1><<<dim3(480, 8), 256, 0, stream>>>(proj_b34, W1t, b1, nullptr, hid, 1024, 256);
    gemm_mfma<0,1,0><<<dim3(480, 2), 256, 0, stream>>>(hid, W2t, b2, ffnout, nullptr, 256, 1024);
    add_ln4<1><<<15360, 256, 0, stream>>>(nullptr, nullptr, proj_b34, ffnout,
                                          ln2_g, ln2_b, nullptr, out_vaa, out_aav);
}

// Round 6
// 434.486 us; speedup vs baseline: 5.5418x; 1.1265x over previous
//
#include <hip/hip_runtime.h>
#include <hip/hip_bf16.h>
#include <cstdint>

#define BB 8
#define SS 3840
#define RR (BB*SS)                 // 30720 rows per modality
#define NHALF ((size_t)RR * 256)   // elems per half plane

typedef short s16x8 __attribute__((ext_vector_type(8)));
typedef float f32x4 __attribute__((ext_vector_type(4)));

__device__ __forceinline__ ushort f2bf(float f) {
    uint32_t u = __builtin_bit_cast(uint32_t, f);
    u += 0x7FFFu + ((u >> 16) & 1u);
    return (ushort)(u >> 16);
}
__device__ __forceinline__ float bf2f(ushort h) {
    return __builtin_bit_cast(float, (uint32_t)h << 16);
}

#define GLDS16(gp, lp) __builtin_amdgcn_global_load_lds( \
    (const __attribute__((address_space(1))) uint32_t*)(gp), \
    (__attribute__((address_space(3))) uint32_t*)(lp), 16, 0, 0)

// ---------------- all weight prep in one kernel ----------------
// Segments: Wv 65536, Wo 32768, Wa 32768, Wp 65536, W1 262144, W2 262144, boa 256.
__global__ __launch_bounds__(256) void wtrans_all(
    const float* __restrict__ Wv, const float* __restrict__ Wo,
    const float* __restrict__ Wa, const float* __restrict__ Wp,
    const float* __restrict__ W1, const float* __restrict__ W2,
    const float* __restrict__ bo, const float* __restrict__ ba,
    ushort* __restrict__ Wvt, ushort* __restrict__ Woat, ushort* __restrict__ Wpt,
    ushort* __restrict__ W1t, ushort* __restrict__ W2t, float* __restrict__ boa)
{
    int e = blockIdx.x * 256 + threadIdx.x;
    if (e < 65536)       { int k = e >> 8, n = e & 255;  Wvt[n * 256 + k] = f2bf(Wv[e]); }
    else if (e < 98304)  { int i = e - 65536;  int k = i >> 7, n = i & 127;  Woat[n * 256 + k] = f2bf(Wo[i]); }
    else if (e < 131072) { int i = e - 98304;  int k = i >> 7, n = i & 127;  Woat[(n + 128) * 256 + k] = f2bf(Wa[i]); }
    else if (e < 196608) { int i = e - 131072; int k = i >> 8, n = i & 255;  Wpt[n * 256 + k] = f2bf(Wp[i]); }
    else if (e < 458752) { int i = e - 196608; int k = i >> 10, n = i & 1023; W1t[n * 256 + k] = f2bf(W1[i]); }
    else if (e < 720896) { int i = e - 458752; int k = i >> 8, n = i & 255;  W2t[(size_t)n * 1024 + k] = f2bf(W2[i]); }
    else if (e < 721152) { int t = e - 720896; boa[t] = (t < 128) ? bo[t] : ba[t - 128]; }
}

// ---------------- pack both modalities: src_bf, q_bf = bf16(src), bf16(src+pos) ----------------
__global__ __launch_bounds__(256) void pack2_cat(
    const float* __restrict__ vs, const float* __restrict__ as_,
    const float* __restrict__ vp, const float* __restrict__ ap,
    ushort* __restrict__ sb, ushort* __restrict__ qb)
{
    const int n4 = (int)(NHALF / 4);
    int i = blockIdx.x * 256 + threadIdx.x;
    int j = (i < n4) ? i : i - n4;
    const float4* s4 = (const float4*)((i < n4) ? vs : as_);
    const float4* p4 = (const float4*)((i < n4) ? vp : ap);
    float4 a = s4[j];
    float4 b = p4[j];
    ushort4 u, v;
    u.x = f2bf(a.x); u.y = f2bf(a.y); u.z = f2bf(a.z); u.w = f2bf(a.w);
    v.x = f2bf(a.x + b.x); v.y = f2bf(a.y + b.y); v.z = f2bf(a.z + b.z); v.w = f2bf(a.w + b.w);
    ((ushort4*)sb)[i] = u;
    ((ushort4*)qb)[i] = v;
}

// ---------------- fused value+offaw GEMM (batched over both halves), 4 waves 128x128 ----------------
__global__ __launch_bounds__(256) void gemm_fused(
    const ushort* __restrict__ Av0, const ushort* __restrict__ Av1,
    const ushort* __restrict__ Ao0, const ushort* __restrict__ Ao1,
    const ushort* __restrict__ WvT, const ushort* __restrict__ WoT,
    const float* __restrict__ bv, const float* __restrict__ boa,
    ushort* __restrict__ val_out,
    float* __restrict__ loc0, float* __restrict__ loc1,
    float* __restrict__ aw0, float* __restrict__ aw1,
    const float* __restrict__ ref0, const float* __restrict__ ref1,
    const int* __restrict__ ts0, const int* __restrict__ ts1,
    const unsigned char* __restrict__ mask0, const unsigned char* __restrict__ mask1)
{
    __shared__ ushort As[128 * 64];
    __shared__ ushort Bs[128 * 64];
    const int tid = threadIdx.x;
    const int lane = tid & 63;
    const int wid = tid >> 6;
    const int wr = wid >> 1, wc = wid & 1;
    const int job = blockIdx.y >> 1;
    const int bn = (blockIdx.y & 1) << 7;
    const int bm = blockIdx.x << 7;
    const int half = bm >= RR;
    const int bmL = half ? bm - RR : bm;
    const int l15 = lane & 15;
    const int l4 = lane >> 4;

    const ushort* A = job ? (half ? Ao1 : Ao0) : (half ? Av1 : Av0);
    const ushort* Wt = job ? WoT : WvT;
    A += (size_t)bmL * 256;

    f32x4 acc[4][4] = {};

    for (int k0 = 0; k0 < 256; k0 += 64) {
        #pragma unroll
        for (int r = 0; r < 4; ++r) {
            int base = r * 256 + (wid << 6);
            int idx = base + lane;
            int row = idx >> 3, sl = idx & 7;
            int ch = sl ^ (row & 7);
            GLDS16(&A[(size_t)row * 256 + k0 + ch * 8], &As[base << 3]);
        }
        #pragma unroll
        for (int r = 0; r < 4; ++r) {
            int base = r * 256 + (wid << 6);
            int idx = base + lane;
            int col = idx >> 3, sl = idx & 7;
            int ch = sl ^ (col & 7);
            GLDS16(&Wt[(size_t)(bn + col) * 256 + k0 + ch * 8], &Bs[base << 3]);
        }
        __syncthreads();
        #pragma unroll
        for (int ks = 0; ks < 2; ++ks) {
            s16x8 af[4], bf[4];
            const int k16 = ks * 4 + l4;
            #pragma unroll
            for (int m = 0; m < 4; ++m) {
                int row = (wr << 6) + (m << 4) + l15;
                af[m] = *(const s16x8*)&As[(row << 6) + ((k16 ^ (row & 7)) << 3)];
            }
            #pragma unroll
            for (int n = 0; n < 4; ++n) {
                int col = (wc << 6) + (n << 4) + l15;
                bf[n] = *(const s16x8*)&Bs[(col << 6) + ((k16 ^ (col & 7)) << 3)];
            }
            #pragma unroll
            for (int m = 0; m < 4; ++m)
                #pragma unroll
                for (int n = 0; n < 4; ++n)
                    acc[m][n] = __builtin_amdgcn_mfma_f32_16x16x32_bf16(af[m], bf[n], acc[m][n], 0, 0, 0);
        }
        __syncthreads();
    }

    const int l4r = l4 << 2;
    if (job == 0) {
        const unsigned char* mk = half ? mask1 : mask0;
        ushort* vo = val_out + (size_t)half * NHALF;
        #pragma unroll
        for (int m = 0; m < 4; ++m) {
            #pragma unroll
            for (int r = 0; r < 4; ++r) {
                const int rowL = bmL + (wr << 6) + (m << 4) + l4r + r;
                const int b = rowL / SS;
                const int s = rowL - b * SS;
                const float mz = mk[rowL] ? 0.f : 1.f;
                const size_t rb = ((size_t)(b * 8) * SS + s) * 32;
                #pragma unroll
                for (int n = 0; n < 4; ++n) {
                    const int col = bn + (wc << 6) + (n << 4) + l15;
                    const int h = col >> 5, d = col & 31;
                    vo[rb + (size_t)h * (SS * 32) + d] = f2bf((acc[m][n][r] + bv[col]) * mz);
                }
            }
        }
    } else if (bn == 0) {
        const float* rf = half ? ref1 : ref0;
        const int* tsp = half ? ts1 : ts0;
        const int l = l15 >> 2;
        const float T = (float)tsp[l];
        float* lo = half ? loc1 : loc0;
        #pragma unroll
        for (int m = 0; m < 4; ++m) {
            #pragma unroll
            for (int r = 0; r < 4; ++r) {
                const int rowL = bmL + (wr << 6) + (m << 4) + l4r + r;
                const float refv = rf[(size_t)rowL * 4 + l];
                #pragma unroll
                for (int n = 0; n < 4; ++n) {
                    const int cc = (wc << 6) + (n << 4) + l15;
                    lo[(size_t)rowL * 128 + cc] = refv + (acc[m][n][r] + boa[cc]) / T;
                }
            }
        }
    } else {
        float* ao = half ? aw1 : aw0;
        #pragma unroll
        for (int m = 0; m < 4; ++m) {
            #pragma unroll
            for (int r = 0; r < 4; ++r) {
                const int rowL = bmL + (wr << 6) + (m << 4) + l4r + r;
                #pragma unroll
                for (int n = 0; n < 4; ++n) {
                    const int cc = (wc << 6) + (n << 4) + l15;
                    float c = acc[m][n][r] + boa[128 + cc];
                    float mx = c;
                    #pragma unroll
                    for (int o = 1; o < 16; o <<= 1) mx = fmaxf(mx, __shfl_xor(mx, o));
                    float e = __expf(c - mx);
                    float sm = e;
                    #pragma unroll
                    for (int o = 1; o < 16; o <<= 1) sm += __shfl_xor(sm, o);
                    ao[(size_t)rowL * 128 + cc] = e / sm;
                }
            }
        }
    }
}

// ---------------- 8-wave 128x256 GEMM with fused epilogues ----------------
// EPI 0: + bias -> bf16 (proj P34)
// EPI 1: + bias + f32 residual (res0/res1 by half) -> LN(g,be) -> bf16 (proj+LN1, P12)
// EPI 2: + bias -> relu -> bf16 (FFN W1, N=1024)
// EPI 3: + bias + bf16 residual -> LN(g,be) -> f32 to of0/of1 by half (FFN W2+LN2)
template<int EPI>
__global__ __launch_bounds__(512) void gemm256(
    const ushort* __restrict__ A, const ushort* __restrict__ Wt,
    const float* __restrict__ bias, int N, int K,
    ushort* __restrict__ outb,
    const float* __restrict__ res0, const float* __restrict__ res1,
    const ushort* __restrict__ resb,
    const float* __restrict__ g, const float* __restrict__ be,
    float* __restrict__ of0, float* __restrict__ of1)
{
    __shared__ ushort As[128 * 64];
    __shared__ ushort Bs[256 * 64];
    __shared__ float redS[128][4];
    __shared__ float redQ[128][4];
    __shared__ float redM[128];
    __shared__ float redR[128];

    const int tid = threadIdx.x;
    const int lane = tid & 63;
    const int wid = tid >> 6;          // 0..7
    const int wr = wid >> 2, wc = wid & 3;
    const int bm = blockIdx.x << 7;
    const int bn = blockIdx.y << 8;
    const int l15 = lane & 15;
    const int l4 = lane >> 4;

    f32x4 acc[4][4] = {};

    for (int k0 = 0; k0 < K; k0 += 64) {
        #pragma unroll
        for (int r = 0; r < 2; ++r) {
            int base = r * 512 + (wid << 6);
            int idx = base + lane;
            int row = idx >> 3, sl = idx & 7;
            int ch = sl ^ (row & 7);
            GLDS16(&A[(size_t)(bm + row) * K + k0 + ch * 8], &As[base << 3]);
        }
        #pragma unroll
        for (int r = 0; r < 4; ++r) {
            int base = r * 512 + (wid << 6);
            int idx = base + lane;
            int col = idx >> 3, sl = idx & 7;
            int ch = sl ^ (col & 7);
            GLDS16(&Wt[(size_t)(bn + col) * K + k0 + ch * 8], &Bs[base << 3]);
        }
        __syncthreads();
        #pragma unroll
        for (int ks = 0; ks < 2; ++ks) {
            s16x8 af[4], bf[4];
            const int k16 = ks * 4 + l4;
            #pragma unroll
            for (int m = 0; m < 4; ++m) {
                int row = (wr << 6) + (m << 4) + l15;
                af[m] = *(const s16x8*)&As[(row << 6) + ((k16 ^ (row & 7)) << 3)];
            }
            #pragma unroll
            for (int n = 0; n < 4; ++n) {
                int col = (wc << 6) + (n << 4) + l15;
                bf[n] = *(const s16x8*)&Bs[(col << 6) + ((k16 ^ (col & 7)) << 3)];
            }
            #pragma unroll
            for (int m = 0; m < 4; ++m)
                #pragma unroll
                for (int n = 0; n < 4; ++n)
                    acc[m][n] = __builtin_amdgcn_mfma_f32_16x16x32_bf16(af[m], bf[n], acc[m][n], 0, 0, 0);
        }
        __syncthreads();
    }

    const int half = bm >= RR;
    const int bmL = half ? bm - RR : bm;

    if (EPI == 0 || EPI == 2) {
        #pragma unroll
        for (int m = 0; m < 4; ++m) {
            #pragma unroll
            for (int r = 0; r < 4; ++r) {
                const int row = bm + (wr << 6) + (m << 4) + (l4 << 2) + r;
                #pragma unroll
                for (int n = 0; n < 4; ++n) {
                    const int col = bn + (wc << 6) + (n << 4) + l15;
                    float c = acc[m][n][r] + bias[col];
                    if (EPI == 2) c = fmaxf(c, 0.f);
                    outb[(size_t)row * N + col] = f2bf(c);
                }
            }
        }
        return;
    }

    // EPI 1/3: add bias + residual into acc, accumulate per-row partials
    #pragma unroll
    for (int m = 0; m < 4; ++m) {
        #pragma unroll
        for (int r = 0; r < 4; ++r) {
            const int rowb = (wr << 6) + (m << 4) + (l4 << 2) + r;  // 0..127 block row
            float s1 = 0.f, s2 = 0.f;
            #pragma unroll
            for (int n = 0; n < 4; ++n) {
                const int col = (wc << 6) + (n << 4) + l15;
                float x = acc[m][n][r] + bias[col];
                if (EPI == 1) {
                    const float* res = half ? res1 : res0;
                    x += res[(size_t)(bmL + rowb) * 256 + col];
                } else {
                    x += bf2f(resb[(size_t)(bm + rowb) * 256 + col]);
                }
                acc[m][n][r] = x;
                s1 += x;
                s2 += x * x;
            }
            #pragma unroll
            for (int o = 1; o < 16; o <<= 1) {
                s1 += __shfl_xor(s1, o);
                s2 += __shfl_xor(s2, o);
            }
            if (l15 == 0) { redS[rowb][wc] = s1; redQ[rowb][wc] = s2; }
        }
    }
    __syncthreads();
    if (tid < 128) {
        const float S1 = redS[tid][0] + redS[tid][1] + redS[tid][2] + redS[tid][3];
        const float S2 = redQ[tid][0] + redQ[tid][1] + redQ[tid][2] + redQ[tid][3];
        const float mu = S1 * (1.f / 256.f);
        float var = S2 * (1.f / 256.f) - mu * mu;
        var = fmaxf(var, 0.f);
        redM[tid] = mu;
        redR[tid] = rsqrtf(var + 1e-5f);
    }
    __syncthreads();
    #pragma unroll
    for (int m = 0; m < 4; ++m) {
        #pragma unroll
        for (int r = 0; r < 4; ++r) {
            const int rowb = (wr << 6) + (m << 4) + (l4 << 2) + r;
            const float mu = redM[rowb];
            const float rs = redR[rowb];
            #pragma unroll
            for (int n = 0; n < 4; ++n) {
                const int col = (wc << 6) + (n << 4) + l15;
                const float y = (acc[m][n][r] - mu) * rs * g[col] + be[col];
                if (EPI == 1) {
                    outb[(size_t)(bm + rowb) * 256 + col] = f2bf(y);
                } else {
                    float* of = half ? of1 : of0;
                    of[(size_t)(bmL + rowb) * 256 + col] = y;
                }
            }
        }
    }
}

// ---------------- deformable sampling (head-major value, batched halves) ----------------
struct Desc { float wa, wb; int oa, ob; };

__global__ __launch_bounds__(256) void msda_sample(
    const ushort* __restrict__ value,
    const float* __restrict__ l0, const float* __restrict__ l1,
    const float* __restrict__ a0, const float* __restrict__ a1,
    const int* __restrict__ ts0, const int* __restrict__ lsi0,
    const int* __restrict__ ts1, const int* __restrict__ lsi1,
    ushort* __restrict__ out)
{
    __shared__ Desc ds[512];
    const int tid = threadIdx.x;
    const int row0 = blockIdx.x << 2;
    const int half = row0 >= RR;
    const int rowL0 = half ? row0 - RR : row0;
    const float* loc = half ? l1 : l0;
    const float* aw  = half ? a1 : a0;
    const int* ts  = half ? ts1 : ts0;
    const int* lsi = half ? lsi1 : lsi0;
    const ushort* val = value + (size_t)half * NHALF;

    #pragma unroll
    for (int d = tid; d < 512; d += 256) {
        const int rl = d >> 7;
        const int rem = d & 127;
        const int l = (rem >> 2) & 3;
        const int h = rem >> 4;
        const int rowL = rowL0 + rl;
        const float lc = loc[(size_t)rowL * 128 + rem];
        const float w  = aw[(size_t)rowL * 128 + rem];
        const int T = ts[l];
        const int s0 = lsi[l];
        const int b = rowL / SS;
        const float pos = lc * (float)T - 0.5f;
        const float x0 = floorf(pos);
        const float w1 = pos - x0;
        const int i0 = (int)x0;
        const int i1 = i0 + 1;
        const int base = (b * 8 + h) * SS + s0;
        Desc e;
        e.wa = (i0 >= 0 && i0 < T) ? w * (1.f - w1) : 0.f;
        e.wb = (i1 >= 0 && i1 < T) ? w * w1 : 0.f;
        const int ia = min(max(i0, 0), T - 1);
        const int ib = min(max(i1, 0), T - 1);
        e.oa = (base + ia) << 5;
        e.ob = (base + ib) << 5;
        ds[d] = e;
    }
    __syncthreads();

    const int rl = tid >> 6;
    const int h  = (tid >> 3) & 7;
    const int cq = tid & 7;
    const ushort* vb = val + cq * 4;
    const Desc* dd = &ds[rl * 128 + h * 16];

    f32x4 acc0 = {}, acc1 = {};
    #pragma unroll
    for (int lp = 0; lp < 16; lp += 2) {
        const Desc e0 = dd[lp];
        const Desc e1 = dd[lp + 1];
        const uint2 A0 = *(const uint2*)(vb + e0.oa);
        const uint2 B0 = *(const uint2*)(vb + e0.ob);
        const uint2 A1 = *(const uint2*)(vb + e1.oa);
        const uint2 B1 = *(const uint2*)(vb + e1.ob);
        #pragma unroll
        for (int c = 0; c < 2; ++c) {
            const uint32_t ua = (c ? A0.y : A0.x), ub = (c ? B0.y : B0.x);
            const uint32_t va = (c ? A1.y : A1.x), vw = (c ? B1.y : B1.x);
            acc0[2*c+0] = fmaf(e0.wa, __builtin_bit_cast(float, ua << 16), acc0[2*c+0]);
            acc0[2*c+1] = fmaf(e0.wa, __builtin_bit_cast(float, ua & 0xFFFF0000u), acc0[2*c+1]);
            acc0[2*c+0] = fmaf(e0.wb, __builtin_bit_cast(float, ub << 16), acc0[2*c+0]);
            acc0[2*c+1] = fmaf(e0.wb, __builtin_bit_cast(float, ub & 0xFFFF0000u), acc0[2*c+1]);
            acc1[2*c+0] = fmaf(e1.wa, __builtin_bit_cast(float, va << 16), acc1[2*c+0]);
            acc1[2*c+1] = fmaf(e1.wa, __builtin_bit_cast(float, va & 0xFFFF0000u), acc1[2*c+1]);
            acc1[2*c+0] = fmaf(e1.wb, __builtin_bit_cast(float, vw << 16), acc1[2*c+0]);
            acc1[2*c+1] = fmaf(e1.wb, __builtin_bit_cast(float, vw & 0xFFFF0000u), acc1[2*c+1]);
        }
    }
    ushort4 o;
    o.x = f2bf(acc0[0] + acc1[0]);
    o.y = f2bf(acc0[1] + acc1[1]);
    o.z = f2bf(acc0[2] + acc1[2]);
    o.w = f2bf(acc0[3] + acc1[3]);
    *(ushort4*)&out[(size_t)(row0 + rl) * 256 + h * 32 + cq * 4] = o;
}

extern "C" void kernel_launch(void* const* d_in, const int* in_sizes, int n_in,
                              void* d_out, int out_size, void* d_ws, size_t ws_size,
                              hipStream_t stream) {
    const float* video_src = (const float*)d_in[0];
    const float* audio_src = (const float*)d_in[1];
    const float* video_pos = (const float*)d_in[2];
    const float* audio_pos = (const float*)d_in[3];
    const float* video_ref = (const float*)d_in[4];
    const float* audio_ref = (const float*)d_in[5];
    const int*   video_ts  = (const int*)d_in[6];
    const int*   video_lsi = (const int*)d_in[7];
    const unsigned char* video_mask = (const unsigned char*)d_in[8];
    const int*   audio_ts  = (const int*)d_in[9];
    const int*   audio_lsi = (const int*)d_in[10];
    const unsigned char* audio_mask = (const unsigned char*)d_in[11];
    const float* Wv = (const float*)d_in[12];
    const float* bv = (const float*)d_in[13];
    const float* Wo = (const float*)d_in[14];
    const float* bo = (const float*)d_in[15];
    const float* Wa = (const float*)d_in[16];
    const float* ba = (const float*)d_in[17];
    const float* Wp = (const float*)d_in[18];
    const float* bp = (const float*)d_in[19];
    const float* ln1_g = (const float*)d_in[20];
    const float* ln1_b = (const float*)d_in[21];
    const float* W1 = (const float*)d_in[22];
    const float* b1 = (const float*)d_in[23];
    const float* W2 = (const float*)d_in[24];
    const float* b2 = (const float*)d_in[25];
    const float* ln2_g = (const float*)d_in[26];
    const float* ln2_b = (const float*)d_in[27];

    float* out = (float*)d_out;
    const size_t n = NHALF;
    float* out_aav  = out;
    float* out_vaa  = out + n;
    float* out_vloc = out + 2 * n;
    float* out_vaw  = out + 2 * n + n / 2;
    float* out_aloc = out + 3 * n;
    float* out_aaw  = out + 3 * n + n / 2;

    const size_t UB = NHALF * 2;   // one bf16 plane, bytes
    char* base = (char*)d_ws;
    ushort* src_cat   = (ushort*)(base + 0 * UB);   // P12
    ushort* q_cat     = (ushort*)(base + 2 * UB);   // P12
    float*  loc_tmp   = (float*) (base + 4 * UB);   // P12
    float*  aw_tmp    = (float*) (base + 6 * UB);   // P12
    ushort* hid       = (ushort*)(base + 0 * UB);   // P34 FFN hidden [0,8U)
    ushort* value_cat = (ushort*)(base + 8 * UB);
    ushort* samp_cat  = (ushort*)(base + 10 * UB);
    ushort* vb_cat    = (ushort*)(base + 12 * UB);
    ushort* proj_b34  = (ushort*)(base + 12 * UB);  // overwrites vb_cat after P34 gemm_fused
    ushort* Wvt  = (ushort*)(base + 14 * UB);
    ushort* Woat = Wvt + 65536;
    ushort* Wpt  = Woat + 65536;
    ushort* W1t  = Wpt + 65536;
    ushort* W2t  = W1t + 262144;
    float*  boa  = (float*)(W2t + 262144);

    wtrans_all<<<2817, 256, 0, stream>>>(Wv, Wo, Wa, Wp, W1, W2, bo, ba,
                                         Wvt, Woat, Wpt, W1t, W2t, boa);
    pack2_cat<<<15360, 256, 0, stream>>>(video_src, audio_src, video_pos, audio_pos,
                                         src_cat, q_cat);

    // ---- Phase 1+2: self-attention ----
    gemm_fused<<<dim3(480, 4), 256, 0, stream>>>(
        src_cat, src_cat + NHALF, q_cat, q_cat + NHALF,
        Wvt, Woat, bv, boa, value_cat,
        loc_tmp, loc_tmp + (size_t)RR * 128, aw_tmp, aw_tmp + (size_t)RR * 128,
        video_ref, audio_ref, video_ts, audio_ts, video_mask, audio_mask);
    msda_sample<<<15360, 256, 0, stream>>>(
        value_cat, loc_tmp, loc_tmp + (size_t)RR * 128, aw_tmp, aw_tmp + (size_t)RR * 128,
        video_ts, video_lsi, audio_ts, audio_lsi, samp_cat);
    // proj + residual + LN1 -> vb_cat (bf16)
    gemm256<1><<<dim3(480, 1), 512, 0, stream>>>(
        samp_cat, Wpt, bp, 256, 256, vb_cat,
        video_src, audio_src, nullptr, ln1_g, ln1_b, nullptr, nullptr);

    // ---- Phase 3+4: cross-attention + FFN ----
    gemm_fused<<<dim3(480, 4), 256, 0, stream>>>(
        vb_cat, vb_cat + NHALF,
        vb_cat + NHALF, vb_cat,
        Wvt, Woat, bv, boa, value_cat,
        out_aloc, out_vloc, out_aaw, out_vaw,
        audio_ref, video_ref, video_ts, audio_ts, video_mask, audio_mask);
    msda_sample<<<15360, 256, 0, stream>>>(
        value_cat, out_aloc, out_vloc, out_aaw, out_vaw,
        video_ts, video_lsi, audio_ts, audio_lsi, samp_cat);
    // proj (plain) -> proj_b34
    gemm256<0><<<dim3(480, 1), 512, 0, stream>>>(
        samp_cat, Wpt, bp, 256, 256, proj_b34,
        nullptr, nullptr, nullptr, nullptr, nullptr, nullptr, nullptr);
    // FFN W1 + relu -> hid
    gemm256<2><<<dim3(480, 4), 512, 0, stream>>>(
        proj_b34, W1t, b1, 1024, 256, hid,
        nullptr, nullptr, nullptr, nullptr, nullptr, nullptr, nullptr);
    // FFN W2 + residual + LN2 -> out planes (f32)
    gemm256<3><<<dim3(480, 1), 512, 0, stream>>>(
        hid, W2t, b2, 256, 1024, nullptr,
        nullptr, nullptr, proj_b34, ln2_g, ln2_b, out_vaa, out_aav);
}